// Round 7
// baseline (1328.059 us; speedup 1.0000x reference)
//
#include <hip/hip_runtime.h>
#include <hip/hip_bf16.h>
#include <math.h>

using bf16 = __hip_bfloat16;
typedef short v8s __attribute__((ext_vector_type(8)));
typedef float v4f __attribute__((ext_vector_type(4)));

#define B_ 2
#define S_ 2048
#define DIM_ 2048
#define H_ 16
#define QL_ 1536
#define KVL_ 512
#define NOPE_ 128
#define ROPE_ 64
#define QKH_ 192
#define DQK_ 576
#define LOG2E 1.4426950408889634f
#define SCALE_ 0.07216878364870323f   // 192^-0.5

__device__ __forceinline__ float bf2f(bf16 x){ return __bfloat162float(x); }
__device__ __forceinline__ bf16 f2bf(float x){ return __float2bfloat16(x); }
union bfu { bf16 b; short s; };
__device__ __forceinline__ short f2s(float x){ bfu u; u.b = __float2bfloat16(x); return u.s; }
__device__ __forceinline__ v4f mfma16(v8s a, v8s b, v4f c){
    return __builtin_amdgcn_mfma_f32_16x16x32_bf16(a, b, c, 0, 0, 0);
}
__device__ __forceinline__ v4f vzero(){ v4f z = {0.f,0.f,0.f,0.f}; return z; }

// No-drain block barrier: orders LDS ops (lgkmcnt(0)) but leaves global loads in flight.
__device__ __forceinline__ void sync_nodrain(){
    asm volatile("s_waitcnt lgkmcnt(0)" ::: "memory");
    __builtin_amdgcn_s_barrier();
    asm volatile("" ::: "memory");
}
// Counted-vmcnt barriers (T4): wait for oldest loads only, keep newer ones in flight.
#define BAR_VM(N) do { \
    asm volatile("s_waitcnt vmcnt(" #N ") lgkmcnt(0)" ::: "memory"); \
    __builtin_amdgcn_s_barrier(); \
    asm volatile("" ::: "memory"); \
} while(0)

// async global->LDS, 16B per lane. LDS dest is wave-uniform base (+ lane*16 by HW);
// global src is per-lane (pre-swizzled for bank-conflict-free LDS reads).
__device__ __forceinline__ void gload16(const void* g, void* l){
    __builtin_amdgcn_global_load_lds(
        (const __attribute__((address_space(1))) unsigned int*)g,
        (__attribute__((address_space(3))) unsigned int*)l, 16, 0, 0);
}

// load 8 contiguous elems as bf16 fragment; f32 -> convert
__device__ __forceinline__ v8s ld8(const void* base, long e, bool f32){
    if (f32){
        const float4* p = reinterpret_cast<const float4*>((const float*)base + e);
        float4 a = p[0], b = p[1];
        v8s r;
        r[0]=f2s(a.x); r[1]=f2s(a.y); r[2]=f2s(a.z); r[3]=f2s(a.w);
        r[4]=f2s(b.x); r[5]=f2s(b.y); r[6]=f2s(b.z); r[7]=f2s(b.w);
        return r;
    }
    return *reinterpret_cast<const v8s*>((const bf16*)base + e);
}
__device__ __forceinline__ float ld1(const void* base, long e, bool f32){
    return f32 ? ((const float*)base)[e] : bf2f(((const bf16*)base)[e]);
}

// ---------------- dtype probe ----------------
__global__ void detect_k(const unsigned* fc, int* flag){
    if (threadIdx.x == 0 && blockIdx.x == 0)
        *flag = (*fc == 0x3f800000u) ? 0 : 1;   // 0 = fp32 buffers, 1 = bf16 buffers
}

// ---------------- gemm128: C = A @ Bt^T, 128x128 tile, m97 structure ----------------
// 4 waves, each computes a 64x64 quadrant (acc 4x4 v4f = 64 AGPR). BK=32.
// LDS 32 KB: 2 buffers x (A 8KB | B 8KB). Row = 64 B, so the XOR swizzle mask must
// stay within bits 4-5: scol = col ^ (((row>>1)&3)<<4). Read pattern (16 lanes, rows
// r..r+15, fixed 16B col) then hits an 8-row bank period {0,16,4,20,8,24,12,28} ->
// 2 lanes/bank = conflict-free. (R6 used (row&7)<<4: bit 6 escapes the 64-B row ->
// wrong data + LDS OOB at row 127 of buffer1/B -> the R6 abort.)
// bf16 operands: global_load_lds width 16 with pre-swizzled global source.
// f32 external operands: reg-stage float4x2 -> convert -> swizzled ds_write_b128.
// One barrier per K-step; staged loads for step k+1 stay in flight across compute(k).
__global__ __launch_bounds__(256) void gemm128(
    const void* __restrict__ A, long lda, int aExt,
    const void* __restrict__ Bt, long ldb, int bExt,
    void* __restrict__ C, long ldc, int cExt,
    int K, const int* __restrict__ gf)
{
    const bool f32 = (*gf == 0);
    const bool a32 = aExt && f32, b32 = bExt && f32, c32 = cExt && f32;
    __shared__ __align__(16) char smc[32768];
    const int tid = threadIdx.x;
    const int w = tid >> 6, lane = tid & 63, quad = lane >> 4, l15 = lane & 15;
    const int wm = w & 1, wn = w >> 1;
    // bijective XCD swizzle (grid size % 8 == 0 guaranteed by launcher)
    const int nx = gridDim.x;
    const int n = nx * gridDim.y;
    const int lin = blockIdx.y * nx + blockIdx.x;
    const int cpx = n >> 3;
    const int swzb = (lin & 7) * cpx + (lin >> 3);
    const int m0 = (swzb / nx) * 128, n0 = (swzb % nx) * 128;

    v4f acc[16];
    #pragma unroll
    for (int i = 0; i < 16; ++i) acc[i] = vzero();

    const int nk = K >> 5;

    // ---- stage one matrix panel (128 rows x 32 cols) for K-step into buf
    auto stage = [&](const void* base, long ldE, bool e32, int r0, int k0, char* buf){
        #pragma unroll
        for (int j = 0; j < 2; ++j) {
            int f = (j * 256 + tid) * 16;
            int row = f >> 6, col = f & 63;
            int scol = col ^ (((row >> 1) & 3) << 4);
            if (e32) {
                const float* p = (const float*)base + (long)(r0 + row) * ldE + k0 + (scol >> 1);
                float4 x = *(const float4*)p;
                float4 y = *(const float4*)(p + 4);
                v8s v;
                v[0]=f2s(x.x); v[1]=f2s(x.y); v[2]=f2s(x.z); v[3]=f2s(x.w);
                v[4]=f2s(y.x); v[5]=f2s(y.y); v[6]=f2s(y.z); v[7]=f2s(y.w);
                *reinterpret_cast<v8s*>(buf + f) = v;
            } else {
                const char* g = (const char*)base + ((long)(r0 + row) * ldE + k0) * 2 + scol;
                gload16(g, buf + j * 4096 + w * 1024);
            }
        }
    };

    // prologue: stage step 0 into buf0
    stage(A,  lda, a32, m0, 0, smc);
    stage(Bt, ldb, b32, n0, 0, smc + 8192);

    for (int ks = 0; ks < nk; ++ks) {
        BAR_VM(0);   // S(ks) resident; all waves done computing step ks-1
        if (ks + 1 < nk) {   // stage S(ks+1): flies under compute(ks)
            char* nb = smc + ((ks + 1) & 1) * 16384;
            stage(A,  lda, a32, m0, (ks + 1) << 5, nb);
            stage(Bt, ldb, b32, n0, (ks + 1) << 5, nb + 8192);
        }
        const char* bufA = smc + (ks & 1) * 16384;
        const char* bufB = bufA + 8192;
        v8s af[4], bfr[4];
        #pragma unroll
        for (int mt = 0; mt < 4; ++mt) {
            int row = wm * 64 + mt * 16 + l15;
            af[mt] = *reinterpret_cast<const v8s*>(bufA + row * 64 + ((quad * 16) ^ (((row >> 1) & 3) << 4)));
        }
        #pragma unroll
        for (int nt = 0; nt < 4; ++nt) {
            int row = wn * 64 + nt * 16 + l15;
            bfr[nt] = *reinterpret_cast<const v8s*>(bufB + row * 64 + ((quad * 16) ^ (((row >> 1) & 3) << 4)));
        }
        __builtin_amdgcn_s_setprio(1);
        #pragma unroll
        for (int mt = 0; mt < 4; ++mt)
            #pragma unroll
            for (int nt = 0; nt < 4; ++nt)
                acc[mt * 4 + nt] = mfma16(af[mt], bfr[nt], acc[mt * 4 + nt]);
        __builtin_amdgcn_s_setprio(0);
    }

    #pragma unroll
    for (int mt = 0; mt < 4; ++mt)
        #pragma unroll
        for (int nt = 0; nt < 4; ++nt)
            #pragma unroll
            for (int r = 0; r < 4; ++r) {
                long off = (long)(m0 + wm * 64 + mt * 16 + quad * 4 + r) * ldc + n0 + wn * 64 + nt * 16 + l15;
                if (c32) ((float*)C)[off] = acc[mt * 4 + nt][r];
                else     ((bf16*)C)[off] = f2bf(acc[mt * 4 + nt][r]);
            }
}

// ---------------- generic GEMM: C = A @ Bt^T (64² tile; used for G3 N=576) ----------------
__global__ __launch_bounds__(256) void gemm_bt(
    const void* __restrict__ A, long lda, long strideA, int aExt,
    const void* __restrict__ Bt, long ldb, long strideB, int bExt,
    void* __restrict__ C, long ldc, long strideC, int cExt,
    int K, const int* __restrict__ gf)
{
    const bool f32 = (*gf == 0);
    const bool a32 = aExt && f32, b32 = bExt && f32, c32 = cExt && f32;
    __shared__ bf16 As[2][64][40];
    __shared__ bf16 Bs[2][64][40];
    const int tid = threadIdx.x;
    const int w = tid >> 6, lane = tid & 63, quad = lane >> 4, l15 = lane & 15;
    const long aoff = (long)blockIdx.z * strideA;
    const long boff = (long)blockIdx.z * strideB;
    const long coff = (long)blockIdx.z * strideC;
    const int m0 = blockIdx.y * 64, n0 = blockIdx.x * 64;
    const int lr = tid >> 2, lc = (tid & 3) * 8;

    v4f acc[4];
    #pragma unroll
    for (int i = 0; i < 4; ++i) acc[i] = vzero();

    v8s av = ld8(A,  aoff + (long)(m0 + lr) * lda + lc, a32);
    v8s bv = ld8(Bt, boff + (long)(n0 + lr) * ldb + lc, b32);

    for (int k0 = 0; k0 < K; k0 += 32) {
        const int bi = (k0 >> 5) & 1;
        *reinterpret_cast<v8s*>(&As[bi][lr][lc]) = av;
        *reinterpret_cast<v8s*>(&Bs[bi][lr][lc]) = bv;
        if (k0 + 32 < K) {
            av = ld8(A,  aoff + (long)(m0 + lr) * lda + k0 + 32 + lc, a32);
            bv = ld8(Bt, boff + (long)(n0 + lr) * ldb + k0 + 32 + lc, b32);
        }
        __syncthreads();
        v8s af = *reinterpret_cast<const v8s*>(&As[bi][w * 16 + l15][quad * 8]);
        #pragma unroll
        for (int nt = 0; nt < 4; ++nt) {
            v8s bfv = *reinterpret_cast<const v8s*>(&Bs[bi][nt * 16 + l15][quad * 8]);
            acc[nt] = mfma16(af, bfv, acc[nt]);
        }
    }
    #pragma unroll
    for (int nt = 0; nt < 4; ++nt)
        #pragma unroll
        for (int r = 0; r < 4; ++r) {
            long off = coff + (long)(m0 + w * 16 + quad * 4 + r) * ldc + n0 + nt * 16 + l15;
            if (c32) ((float*)C)[off] = acc[nt][r];
            else     ((bf16*)C)[off] = f2bf(acc[nt][r]);
        }
}

// ---------------- RMSNorm width 1536 ----
__global__ __launch_bounds__(256) void rmsnorm_q(
    const bf16* __restrict__ in, const void* __restrict__ wt, bf16* __restrict__ out,
    const int* __restrict__ gf)
{
    const bool f32 = (*gf == 0);
    int row = blockIdx.x;
    const bf16* x = in + (long)row * QL_;
    float v[6]; float ss = 0.f;
    #pragma unroll
    for (int i = 0; i < 6; ++i) { v[i] = bf2f(x[threadIdx.x + i * 256]); ss += v[i] * v[i]; }
    #pragma unroll
    for (int off = 1; off < 64; off <<= 1) ss += __shfl_xor(ss, off);
    __shared__ float ws4[4];
    if ((threadIdx.x & 63) == 0) ws4[threadIdx.x >> 6] = ss;
    __syncthreads();
    float rs = rsqrtf((ws4[0] + ws4[1] + ws4[2] + ws4[3]) / (float)QL_ + 1e-6f);
    bf16* o = out + (long)row * QL_;
    #pragma unroll
    for (int i = 0; i < 6; ++i) {
        int c = threadIdx.x + i * 256;
        o[c] = f2bf(v[i] * rs * ld1(wt, c, f32));
    }
}

// ---------------- kv: rmsnorm(512) + rope(64) ----------------
__global__ __launch_bounds__(256) void kv_proc(
    bf16* __restrict__ kvf, const void* __restrict__ wt,
    const void* __restrict__ fcos, const void* __restrict__ fsin,
    const int* __restrict__ gf)
{
    const bool f32 = (*gf == 0);
    int row = blockIdx.x;             // b*2048 + s
    int s = row & (S_ - 1);
    bf16* x = kvf + (long)row * DQK_;
    float v[2]; float ss = 0.f;
    #pragma unroll
    for (int i = 0; i < 2; ++i) { v[i] = bf2f(x[threadIdx.x + i * 256]); ss += v[i] * v[i]; }
    #pragma unroll
    for (int off = 1; off < 64; off <<= 1) ss += __shfl_xor(ss, off);
    __shared__ float ws4[4];
    if ((threadIdx.x & 63) == 0) ws4[threadIdx.x >> 6] = ss;
    __syncthreads();
    float rs = rsqrtf((ws4[0] + ws4[1] + ws4[2] + ws4[3]) / (float)KVL_ + 1e-6f);
    #pragma unroll
    for (int i = 0; i < 2; ++i) {
        int c = threadIdx.x + i * 256;
        x[c] = f2bf(v[i] * rs * ld1(wt, c, f32));
    }
    if (threadIdx.x < 32) {
        int i = threadIdx.x;
        float x0 = bf2f(x[KVL_ + 2 * i]), x1 = bf2f(x[KVL_ + 2 * i + 1]);
        float c = ld1(fcos, s * 32 + i, f32), sn = ld1(fsin, s * 32 + i, f32);
        x[KVL_ + 2 * i]     = f2bf(x0 * c - x1 * sn);
        x[KVL_ + 2 * i + 1] = f2bf(x0 * sn + x1 * c);
    }
}

// ---------------- q pack ----
__global__ __launch_bounds__(512) void q_pack(
    const bf16* __restrict__ qfull, const void* __restrict__ fcos, const void* __restrict__ fsin,
    bf16* __restrict__ qnope, bf16* __restrict__ qpe, const int* __restrict__ gf)
{
    const bool f32 = (*gf == 0);
    int row = blockIdx.x;             // b*2048 + s
    int s = row & (S_ - 1);
    int b = row >> 11;
    const bf16* q = qfull + (long)row * (H_ * QKH_);
    int t = threadIdx.x;
    {   // rope
        int h = t >> 5, i = t & 31;
        float x0 = bf2f(q[h * QKH_ + NOPE_ + 2 * i]);
        float x1 = bf2f(q[h * QKH_ + NOPE_ + 2 * i + 1]);
        float c = ld1(fcos, s * 32 + i, f32), sn = ld1(fsin, s * 32 + i, f32);
        bf16* dst = qpe + ((long)(h * B_ + b) * S_ + s) * ROPE_;
        dst[2 * i]     = f2bf(x0 * c - x1 * sn);
        dst[2 * i + 1] = f2bf(x0 * sn + x1 * c);
    }
    if (t < 256) {  // nope copy
        int h = t >> 4, d0 = (t & 15) * 8;
        v8s v = *reinterpret_cast<const v8s*>(q + h * QKH_ + d0);
        *reinterpret_cast<v8s*>(qnope + ((long)h * 4096 + row) * NOPE_ + d0) = v;
    }
}

// ---------------- V transpose: kvf[:, :512] -> Vt (B, 512, S) ----------------
__global__ __launch_bounds__(256) void v_transpose(
    const bf16* __restrict__ kcomb, bf16* __restrict__ vt)
{
    __shared__ bf16 tile[64][72];
    int b = blockIdx.z, t0 = blockIdx.x * 64, c0 = blockIdx.y * 64;
    int tid = threadIdx.x;
    int r = tid >> 2, sg = tid & 3;
    const bf16* src = kcomb + ((long)b * S_ + t0 + r) * DQK_ + c0 + sg * 16;
    #pragma unroll
    for (int i = 0; i < 2; ++i)
        *reinterpret_cast<v8s*>(&tile[r][sg * 16 + i * 8]) = reinterpret_cast<const v8s*>(src)[i];
    __syncthreads();
    int c = tid >> 2;
    bf16* dst = vt + ((long)b * KVL_ + c0 + c) * S_ + t0 + sg * 16;
    bf16 tmp[16];
    #pragma unroll
    for (int i = 0; i < 16; ++i) tmp[i] = tile[sg * 16 + i][c];
    #pragma unroll
    for (int i = 0; i < 2; ++i)
        reinterpret_cast<v8s*>(dst)[i] = *reinterpret_cast<v8s*>(&tmp[i * 8]);
}

// ---------------- wkv_b nope rows transpose ----------------
__global__ __launch_bounds__(256) void wkvb_t_kernel(
    const void* __restrict__ wkvb, bf16* __restrict__ outp, const int* __restrict__ gf)
{
    const bool f32 = (*gf == 0);
    long idx = (long)blockIdx.x * 256 + threadIdx.x;  // 16*512*128
    int h = (int)(idx >> 16);
    int rem = (int)(idx & 65535);
    int c = rem >> 7, d = rem & 127;
    outp[idx] = f2bf(ld1(wkvb, ((long)(h * 256 + d)) * KVL_ + c, f32));
}

// ---------------- flash attention: 8-wave ctx-split (R4 best: 812 us) ----------------
__global__ __launch_bounds__(512, 2) void attn(
    const bf16* __restrict__ qnope, // (H, 4096, 128)
    const bf16* __restrict__ qpe,   // (H*B, S, 64)
    const bf16* __restrict__ kc,    // (B, S, 576)
    const bf16* __restrict__ vt,    // (B, 512, S)
    const bf16* __restrict__ wkvbt, // (H, 512, 128)
    const void* __restrict__ wkvb,  // external (H*256, 512); rows h*256+128.. = wv
    bf16* __restrict__ oheads,      // (4096, 2048), head h at cols h*128..
    const int* __restrict__ gf)
{
    __shared__ bf16 sm[78848];      // 157696 B
    char* smc = (char*)sm;
    const bool e32 = (*gf == 0);
    const int tid = threadIdx.x;
    const int w = tid >> 6, lane = tid & 63, quad = lane >> 4, l15 = lane & 15;
    const int wr = w & 3, wc = w >> 2;
    const int qb = gridDim.x - 1 - blockIdx.x;   // longest blocks first
    const int bh = blockIdx.y;                    // h*B + b
    const int b = bh & (B_ - 1), h = bh >> 1;
    const int q0 = qb * 64;

    // ---- prologue: q_abs = qnope_tile @ wkvbt_h^T -> qreg[18] A-frags
    #pragma unroll
    for (int i = 0; i < 2; ++i) {   // stage Qn (64x128 -> [64][136])
        int a = tid + i * 512, rr = a >> 4, sg = a & 15;
        *reinterpret_cast<v8s*>(&sm[8704 + rr * 136 + sg * 8]) =
            *reinterpret_cast<const v8s*>(qnope + ((long)h * 4096 + b * 2048 + q0 + rr) * NOPE_ + sg * 8);
    }
    v8s qreg[18];
    for (int p = 0; p < 4; ++p) {
        sync_nodrain();
        #pragma unroll
        for (int i = 0; i < 4; ++i) {   // stage Wt: 128 rows (c-dim) x 128 (d-dim)
            int a = tid + i * 512, rr = a >> 4, sg = a & 15;
            *reinterpret_cast<v8s*>(&sm[17408 + rr * 136 + sg * 8]) =
                *reinterpret_cast<const v8s*>(wkvbt + ((long)h * 512 + p * 128 + rr) * NOPE_ + sg * 8);
        }
        sync_nodrain();
        v4f qacc[4];
        #pragma unroll
        for (int i = 0; i < 4; ++i) qacc[i] = vzero();
        #pragma unroll
        for (int kk = 0; kk < 4; ++kk) {
            v8s aq = *reinterpret_cast<const v8s*>(&sm[8704 + (wr * 16 + l15) * 136 + kk * 32 + quad * 8]);
            #pragma unroll
            for (int nt = 0; nt < 4; ++nt) {
                v8s bw = *reinterpret_cast<const v8s*>(&sm[17408 + (wc * 64 + nt * 16 + l15) * 136 + kk * 32 + quad * 8]);
                qacc[nt] = mfma16(aq, bw, qacc[nt]);
            }
        }
        #pragma unroll
        for (int nt = 0; nt < 4; ++nt)
            #pragma unroll
            for (int r = 0; r < 4; ++r)
                sm[(wr * 16 + quad * 4 + r) * 136 + wc * 64 + nt * 16 + l15] = f2bf(qacc[nt][r]);
        sync_nodrain();
        #pragma unroll
        for (int c2 = 0; c2 < 2; ++c2)
            #pragma unroll
            for (int ks = 0; ks < 2; ++ks)
                qreg[p * 4 + c2 * 2 + ks] =
                    *reinterpret_cast<const v8s*>(&sm[(wr * 16 + l15) * 136 + c2 * 64 + ks * 32 + quad * 8]);
    }
    {   // qpe fragments (d 512..575)
        const bf16* qp = qpe + ((long)bh * S_ + q0 + wr * 16 + l15) * ROPE_;
        qreg[16] = *reinterpret_cast<const v8s*>(qp + quad * 8);
        qreg[17] = *reinterpret_cast<const v8s*>(qp + 32 + quad * 8);
    }
    sync_nodrain();   // prologue LDS reads done before K(0) staging lands

    // ---- staging voffsets (pre-swizzled source; linear LDS dest)
    const char* KbB = (const char*)(kc + (long)b * S_ * DQK_);
    const char* VbB = (const char*)(vt + (long)b * KVL_ * S_);
    unsigned srcK[9], srcV[8];
    #pragma unroll
    for (int j = 0; j < 9; ++j) {   // K tile [64][1152B]
        unsigned f = (unsigned)((j * 512 + tid) * 16);
        unsigned row = f / 1152u;
        unsigned col = f - row * 1152u;
        srcK[j] = row * 1152u + (col ^ ((row & 7u) << 4));
    }
    #pragma unroll
    for (int j = 0; j < 8; ++j) {   // V tile [512][128B]
        unsigned f = (unsigned)((j * 512 + tid) * 16);
        unsigned row = f >> 7, col = f & 127u;
        srcV[j] = row * (unsigned)(S_ * 2) + (col ^ ((row & 7u) << 4));
    }
    const unsigned swz = (unsigned)((l15 & 7) << 4);
    bf16* Psw = sm + 69632 + w * 1152;   // wave-private [16][72]
    char* PswB = (char*)Psw;
    const int nkb = qb + 1;

    // issue K(0)
    #pragma unroll
    for (int j = 0; j < 9; ++j)
        gload16(KbB + srcK[j], smc + j * 8192 + w * 1024);

    float m_run[4], l_run[4];
    v4f o[16];
    #pragma unroll
    for (int i = 0; i < 16; ++i) o[i] = vzero();
    #pragma unroll
    for (int r = 0; r < 4; ++r) { m_run[r] = -3e38f; l_run[r] = 0.f; }

    for (int kb = 0; kb < nkb; ++kb) {
        const int t0 = kb * 64;

        BAR_VM(0);   // K(kb) resident; all waves past PV(kb-1)

        // issue V(kb): flies under QK^T + softmax
        {
            const char* vb = VbB + (long)t0 * 2;
            #pragma unroll
            for (int j = 0; j < 8; ++j)
                gload16(vb + srcV[j], smc + 73728 + j * 8192 + w * 1024);
        }

        // ---- QK^T: 72 MFMAs from swizzled K tile (duplicated across wc pair)
        v4f sacc[4];
        #pragma unroll
        for (int i = 0; i < 4; ++i) sacc[i] = vzero();
        const char* kr = smc + (unsigned)(l15 * 1152);
        __builtin_amdgcn_s_setprio(1);
        #pragma unroll
        for (int g = 0; g < 18; ++g) {
            v8s aq = qreg[g];
            unsigned a0 = ((unsigned)(g * 64 + quad * 16)) ^ swz;
            #pragma unroll
            for (int nt = 0; nt < 4; ++nt) {
                v8s bk = *reinterpret_cast<const v8s*>(kr + nt * 18432 + a0);
                sacc[nt] = mfma16(aq, bk, sacc[nt]);
            }
        }
        __builtin_amdgcn_s_setprio(0);

        sync_nodrain();   // all waves done reading K region
        if (kb + 1 < nkb) {   // issue K(kb+1): flies under softmax + PV
            const char* kbn = KbB + (long)(t0 + 64) * 1152;
            #pragma unroll
            for (int j = 0; j < 9; ++j)
                gload16(kbn + srcK[j], smc + j * 8192 + w * 1024);
        }

        // ---- scale + causal mask
        #pragma unroll
        for (int nt = 0; nt < 4; ++nt) {
            int col = t0 + nt * 16 + l15;
            #pragma unroll
            for (int r = 0; r < 4; ++r) {
                int row = q0 + wr * 16 + quad * 4 + r;
                float s = sacc[nt][r] * SCALE_;
                sacc[nt][r] = (col <= row) ? s : -3e38f;
            }
        }
        // ---- online softmax with exact defer-rescale
        float mx[4];
        #pragma unroll
        for (int r = 0; r < 4; ++r) {
            float m = fmaxf(fmaxf(sacc[0][r], sacc[1][r]), fmaxf(sacc[2][r], sacc[3][r]));
            m = fmaxf(m, __shfl_xor(m, 1));
            m = fmaxf(m, __shfl_xor(m, 2));
            m = fmaxf(m, __shfl_xor(m, 4));
            m = fmaxf(m, __shfl_xor(m, 8));
            mx[r] = m;
        }
        int need = (mx[0] > m_run[0]) | (mx[1] > m_run[1]) | (mx[2] > m_run[2]) | (mx[3] > m_run[3]);
        if (__any(need)) {
            float al[4];
            #pragma unroll
            for (int r = 0; r < 4; ++r) {
                float mnew = fmaxf(m_run[r], mx[r]);
                al[r] = exp2f((m_run[r] - mnew) * LOG2E);
                m_run[r] = mnew;
                l_run[r] *= al[r];
            }
            #pragma unroll
            for (int i = 0; i < 16; ++i)
                #pragma unroll
                for (int r = 0; r < 4; ++r) o[i][r] *= al[r];
        }
        float rsum[4] = {0.f, 0.f, 0.f, 0.f};
        #pragma unroll
        for (int nt = 0; nt < 4; ++nt)
            #pragma unroll
            for (int r = 0; r < 4; ++r) {
                float pv = exp2f((sacc[nt][r] - m_run[r]) * LOG2E);
                rsum[r] += pv;
                Psw[(quad * 4 + r) * 72 + nt * 16 + l15] = f2bf(pv);
            }
        #pragma unroll
        for (int r = 0; r < 4; ++r) {
            float t = rsum[r];
            t += __shfl_xor(t, 1);
            t += __shfl_xor(t, 2);
            t += __shfl_xor(t, 4);
            t += __shfl_xor(t, 8);
            l_run[r] += t;
        }

        // ---- V ready? (K(kb+1)'s 9 loads may remain in flight)
        if (kb + 1 < nkb) { BAR_VM(9); } else { BAR_VM(0); }

        // ---- PV: 32 MFMAs from swizzled V tile (wave's ctx half)
        v8s pa0 = *reinterpret_cast<const v8s*>(PswB + l15 * 144 + quad * 16);
        v8s pa1 = *reinterpret_cast<const v8s*>(PswB + l15 * 144 + 64 + quad * 16);
        const char* vr = smc + 73728 + (unsigned)((wc * 256 + l15) * 128);
        __builtin_amdgcn_s_setprio(1);
        #pragma unroll
        for (int ks = 0; ks < 2; ++ks) {
            v8s pa = ks ? pa1 : pa0;
            unsigned a0 = ((unsigned)(ks * 64 + quad * 16)) ^ swz;
            #pragma unroll
            for (int nt = 0; nt < 16; ++nt) {
                v8s bv = *reinterpret_cast<const v8s*>(vr + nt * 2048 + a0);
                o[nt] = mfma16(pa, bv, o[nt]);
            }
        }
        __builtin_amdgcn_s_setprio(0);
    }

    // ---- epilogue: out_h = (o/l) @ wv_h^T; each wave K=256 partial, exact f32 merge
    sync_nodrain();
    float inv[4];
    #pragma unroll
    for (int r = 0; r < 4; ++r) inv[r] = 1.0f / l_run[r];
    // Po @0: [64][520]
    #pragma unroll
    for (int i = 0; i < 16; ++i)
        #pragma unroll
        for (int r = 0; r < 4; ++r)
            sm[(wr * 16 + quad * 4 + r) * 520 + wc * 256 + i * 16 + l15] = f2bf(o[i][r] * inv[r]);
    v4f oacc[8];
    #pragma unroll
    for (int i = 0; i < 8; ++i) oacc[i] = vzero();

    for (int kcc = 0; kcc < 8; ++kcc) {
        sync_nodrain();
        #pragma unroll
        for (int i = 0; i < 2; ++i) {   // stage both wv halves: [2][128][40]
            int a = wr * 64 + lane + i * 256, rr = a >> 2, sg = a & 3;
            *reinterpret_cast<v8s*>(&sm[36864 + wc * 5120 + rr * 40 + sg * 8]) =
                ld8(wkvb, (long)(h * 256 + 128 + rr) * KVL_ + wc * 256 + kcc * 32 + sg * 8, e32);
        }
        sync_nodrain();
        v8s aq = *reinterpret_cast<const v8s*>(&sm[(wr * 16 + l15) * 520 + wc * 256 + kcc * 32 + quad * 8]);
        #pragma unroll
        for (int nt = 0; nt < 8; ++nt) {
            v8s bw = *reinterpret_cast<const v8s*>(&sm[36864 + wc * 5120 + (nt * 16 + l15) * 40 + quad * 8]);
            oacc[nt] = mfma16(aq, bw, oacc[nt]);
        }
    }
    // merge: wc=1 writes f32 partial, wc=0 adds and stores
    float* Mrg = (float*)(smc + 94208);   // [4][16][128]
    if (wc == 1) {
        #pragma unroll
        for (int nt = 0; nt < 8; ++nt)
            #pragma unroll
            for (int r = 0; r < 4; ++r)
                Mrg[wr * 2048 + (quad * 4 + r) * 128 + nt * 16 + l15] = oacc[nt][r];
    }
    sync_nodrain();
    if (wc == 0) {
        #pragma unroll
        for (int nt = 0; nt < 8; ++nt)
            #pragma unroll
            for (int r = 0; r < 4; ++r)
                oheads[(long)(b * S_ + q0 + wr * 16 + quad * 4 + r) * 2048 + h * 128 + nt * 16 + l15] =
                    f2bf(oacc[nt][r] + Mrg[wr * 2048 + (quad * 4 + r) * 128 + nt * 16 + l15]);
    }
}

extern "C" void kernel_launch(void* const* d_in, const int* in_sizes, int n_in,
                              void* d_out, int out_size, void* d_ws, size_t ws_size,
                              hipStream_t stream) {
    const void* x     = d_in[0];
    const void* fcos  = d_in[1];
    const void* fsin  = d_in[2];
    // d_in[3] = mask (causal) — implemented directly
    const void* wq_a  = d_in[4];
    const void* q_ln  = d_in[5];
    const void* wq_b  = d_in[6];
    const void* wkv_a = d_in[7];
    const void* kv_ln = d_in[8];
    const void* wkv_b = d_in[9];
    const void* wo    = d_in[10];

    // workspace (bf16 elems), peak 30,670,864 elems ~= 58.5 MiB
    bf16* W = (bf16*)d_ws;
    bf16* t0     = W;                 // 6,291,456 (dead after GEMM2)
    bf16* qnope  = W;                 // 8,388,608 (written by q_pack, after t0 dead)
    bf16* qpe    = W + 8388608L;      // 4,194,304
    bf16* qfull  = W + 12582912L;     // 12,582,912 (dead after q_pack)
    bf16* oheads = W + 12582912L;     // 8,388,608 (over qfull)
    bf16* kvf    = W + 25165824L;     // 2,359,296
    bf16* vtb    = W + 27525120L;     // 2,097,152
    bf16* wkvbt  = W + 29622272L;     // 1,048,576
    int*  gflag  = (int*)(W + 30670848L);

    detect_k<<<dim3(1), dim3(64), 0, stream>>>((const unsigned*)fcos, gflag);
    wkvb_t_kernel<<<dim3(4096), dim3(256), 0, stream>>>(wkv_b, wkvbt, gflag);

    // GEMM1: t0 = x @ wq_a^T   (4096 x 1536 x 2048)  [128² tile]
    gemm128<<<dim3(12, 32), dim3(256), 0, stream>>>(
        x, 2048L, 1, wq_a, 2048L, 1, t0, 1536L, 0, 2048, gflag);
    rmsnorm_q<<<dim3(4096), dim3(256), 0, stream>>>(t0, q_ln, t0, gflag);

    // GEMM2: qfull = t0 @ wq_b^T  (4096 x 3072 x 1536)  [128² tile]
    gemm128<<<dim3(24, 32), dim3(256), 0, stream>>>(
        t0, 1536L, 0, wq_b, 1536L, 1, qfull, 3072L, 0, 1536, gflag);

    // GEMM3: kvf = x @ wkv_a^T  (4096 x 576 x 2048)  [64² tile, N not /128]
    gemm_bt<<<dim3(9, 64, 1), dim3(256), 0, stream>>>(
        x, 2048L, 0L, 1, wkv_a, 2048L, 0L, 1, kvf, 576L, 0L, 0, 2048, gflag);

    q_pack<<<dim3(4096), dim3(512), 0, stream>>>(qfull, fcos, fsin, qnope, qpe, gflag);
    kv_proc<<<dim3(4096), dim3(256), 0, stream>>>(kvf, kv_ln, fcos, fsin, gflag);
    v_transpose<<<dim3(32, 8, 2), dim3(256), 0, stream>>>(kvf, vtb);

    // attention (+ on-the-fly q_abs, + fused per-head out projection) -> oheads
    attn<<<dim3(32, 32), dim3(512), 0, stream>>>(
        qnope, qpe, kvf, vtb, wkvbt, wkv_b, oheads, gflag);

    // GEMM7: out = oheads @ wo^T  (4096 x 2048 x 2048)  [128² tile]
    gemm128<<<dim3(16, 32), dim3(256), 0, stream>>>(
        oheads, 2048L, 0, wo, 2048L, 1, d_out, 2048L, 1, 2048, gflag);
}

// Round 8
// 1214.515 us; speedup vs baseline: 1.0935x; 1.0935x over previous
//
#include <hip/hip_runtime.h>
#include <hip/hip_bf16.h>
#include <math.h>

using bf16 = __hip_bfloat16;
typedef short v8s __attribute__((ext_vector_type(8)));
typedef float v4f __attribute__((ext_vector_type(4)));

#define B_ 2
#define S_ 2048
#define DIM_ 2048
#define H_ 16
#define QL_ 1536
#define KVL_ 512
#define NOPE_ 128
#define ROPE_ 64
#define QKH_ 192
#define DQK_ 576
#define LOG2E 1.4426950408889634f
#define SCALE_ 0.07216878364870323f   // 192^-0.5

__device__ __forceinline__ float bf2f(bf16 x){ return __bfloat162float(x); }
__device__ __forceinline__ bf16 f2bf(float x){ return __float2bfloat16(x); }
union bfu { bf16 b; short s; };
__device__ __forceinline__ short f2s(float x){ bfu u; u.b = __float2bfloat16(x); return u.s; }
__device__ __forceinline__ v4f mfma16(v8s a, v8s b, v4f c){
    return __builtin_amdgcn_mfma_f32_16x16x32_bf16(a, b, c, 0, 0, 0);
}
__device__ __forceinline__ v4f vzero(){ v4f z = {0.f,0.f,0.f,0.f}; return z; }

// No-drain block barrier: orders LDS ops (lgkmcnt(0)) but leaves global loads in flight.
__device__ __forceinline__ void sync_nodrain(){
    asm volatile("s_waitcnt lgkmcnt(0)" ::: "memory");
    __builtin_amdgcn_s_barrier();
    asm volatile("" ::: "memory");
}
// Counted-vmcnt barriers (T4): wait for oldest loads only, keep newer ones in flight.
#define BAR_VM(N) do { \
    asm volatile("s_waitcnt vmcnt(" #N ") lgkmcnt(0)" ::: "memory"); \
    __builtin_amdgcn_s_barrier(); \
    asm volatile("" ::: "memory"); \
} while(0)

// async global->LDS, 16B per lane. LDS dest is wave-uniform base (+ lane*16 by HW);
// global src is per-lane (pre-swizzled for bank-conflict-free LDS reads).
__device__ __forceinline__ void gload16(const void* g, void* l){
    __builtin_amdgcn_global_load_lds(
        (const __attribute__((address_space(1))) unsigned int*)g,
        (__attribute__((address_space(3))) unsigned int*)l, 16, 0, 0);
}

// load 8 contiguous elems as bf16 fragment; f32 -> convert
__device__ __forceinline__ v8s ld8(const void* base, long e, bool f32){
    if (f32){
        const float4* p = reinterpret_cast<const float4*>((const float*)base + e);
        float4 a = p[0], b = p[1];
        v8s r;
        r[0]=f2s(a.x); r[1]=f2s(a.y); r[2]=f2s(a.z); r[3]=f2s(a.w);
        r[4]=f2s(b.x); r[5]=f2s(b.y); r[6]=f2s(b.z); r[7]=f2s(b.w);
        return r;
    }
    return *reinterpret_cast<const v8s*>((const bf16*)base + e);
}
__device__ __forceinline__ float ld1(const void* base, long e, bool f32){
    return f32 ? ((const float*)base)[e] : bf2f(((const bf16*)base)[e]);
}

// ---------------- dtype probe ----------------
__global__ void detect_k(const unsigned* fc, int* flag){
    if (threadIdx.x == 0 && blockIdx.x == 0)
        *flag = (*fc == 0x3f800000u) ? 0 : 1;   // 0 = fp32 buffers, 1 = bf16 buffers
}

// ---------------- gemm128 v2: 128x128 tile with ASYNC-SPLIT staging (T14) ----------------
// R7's version stalled serially: f32 staging converted immediately after its loads,
// exposing full L2 latency every K-step (and grids of 1.5-3 blocks/CU can't TLP-hide it).
// v2 splits staging: loads for step ks+1 are ISSUED (f32 -> regs RA/RB, bf16 ->
// global_load_lds) fire-and-forget after the barrier; the convert+ds_write happens at
// the NEXT iteration's top after one exact vmcnt(0). Latency window = full compute phase.
// Hazards: reads(ks-2) < bar(ks-1) < writes(ks); gload(ks+1) issued post-bar(ks) into
// the buffer last read at ks-1 -> 1 lgkm barrier/step suffices. Swizzle: 64-B rows ->
// scol = col ^ (((row>>1)&3)<<4); 16-lane column read = 2 lanes/bank (free).
__global__ __launch_bounds__(256) void gemm128(
    const void* __restrict__ A, long lda, int aExt,
    const void* __restrict__ Bt, long ldb, int bExt,
    void* __restrict__ C, long ldc, int cExt,
    int K, const int* __restrict__ gf)
{
    const bool f32 = (*gf == 0);
    const bool a32 = aExt && f32, b32 = bExt && f32, c32 = cExt && f32;
    __shared__ __align__(16) char smc[32768];
    const int tid = threadIdx.x;
    const int w = tid >> 6, lane = tid & 63, quad = lane >> 4, l15 = lane & 15;
    const int wm = w & 1, wn = w >> 1;
    // bijective XCD swizzle (grid size % 8 == 0 guaranteed by launcher)
    const int nx = gridDim.x;
    const int n = nx * gridDim.y;
    const int lin = blockIdx.y * nx + blockIdx.x;
    const int cpx = n >> 3;
    const int swzb = (lin & 7) * cpx + (lin >> 3);
    const int m0 = (swzb / nx) * 128, n0 = (swzb % nx) * 128;

    // per-thread panel coords: two 16B chunks, swizzled column
    int prow[2], pscol[2];
    #pragma unroll
    for (int j = 0; j < 2; ++j) {
        int f = (j * 256 + tid) * 16;
        prow[j]  = f >> 6;
        pscol[j] = (f & 63) ^ (((prow[j] >> 1) & 3) << 4);
    }

    v4f acc[16];
    #pragma unroll
    for (int i = 0; i < 16; ++i) acc[i] = vzero();
    const int nk = K >> 5;
    float4 RA[4], RB[4];

    // issue loads for one K-step (fire-and-forget)
    auto issueA = [&](int k0, char* panel){
        if (a32) {
            #pragma unroll
            for (int j = 0; j < 2; ++j) {
                const float* p = (const float*)A + (long)(m0 + prow[j]) * lda + k0 + (pscol[j] >> 1);
                RA[j * 2]     = *(const float4*)p;
                RA[j * 2 + 1] = *(const float4*)(p + 4);
            }
        } else {
            #pragma unroll
            for (int j = 0; j < 2; ++j) {
                const char* g = (const char*)A + ((long)(m0 + prow[j]) * lda + k0) * 2 + pscol[j];
                gload16(g, panel + j * 4096 + w * 1024);
            }
        }
    };
    auto issueB = [&](int k0, char* panel){
        if (b32) {
            #pragma unroll
            for (int j = 0; j < 2; ++j) {
                const float* p = (const float*)Bt + (long)(n0 + prow[j]) * ldb + k0 + (pscol[j] >> 1);
                RB[j * 2]     = *(const float4*)p;
                RB[j * 2 + 1] = *(const float4*)(p + 4);
            }
        } else {
            #pragma unroll
            for (int j = 0; j < 2; ++j) {
                const char* g = (const char*)Bt + ((long)(n0 + prow[j]) * ldb + k0) * 2 + pscol[j];
                gload16(g, panel + j * 4096 + w * 1024);
            }
        }
    };
    // convert + ds_write the reg-staged f32 data (no-op for bf16 panels)
    auto writeA = [&](char* panel){
        if (a32) {
            #pragma unroll
            for (int j = 0; j < 2; ++j) {
                int f = (j * 256 + tid) * 16;
                float4 x = RA[j * 2], y = RA[j * 2 + 1];
                v8s v;
                v[0]=f2s(x.x); v[1]=f2s(x.y); v[2]=f2s(x.z); v[3]=f2s(x.w);
                v[4]=f2s(y.x); v[5]=f2s(y.y); v[6]=f2s(y.z); v[7]=f2s(y.w);
                *reinterpret_cast<v8s*>(panel + f) = v;
            }
        }
    };
    auto writeB = [&](char* panel){
        if (b32) {
            #pragma unroll
            for (int j = 0; j < 2; ++j) {
                int f = (j * 256 + tid) * 16;
                float4 x = RB[j * 2], y = RB[j * 2 + 1];
                v8s v;
                v[0]=f2s(x.x); v[1]=f2s(x.y); v[2]=f2s(x.z); v[3]=f2s(x.w);
                v[4]=f2s(y.x); v[5]=f2s(y.y); v[6]=f2s(y.z); v[7]=f2s(y.w);
                *reinterpret_cast<v8s*>(panel + f) = v;
            }
        }
    };

    // prologue: issue L(0)
    issueA(0, smc);
    issueB(0, smc + 8192);

    for (int ks = 0; ks < nk; ++ks) {
        char* cur = smc + (ks & 1) * 16384;
        asm volatile("s_waitcnt vmcnt(0)" ::: "memory");   // L(ks) landed (regs + LDS)
        writeA(cur);
        writeB(cur + 8192);
        sync_nodrain();          // ds_writes visible; nothing newer in flight yet
        if (ks + 1 < nk) {       // issue L(ks+1): flies under the whole compute phase
            char* nxt = smc + ((ks + 1) & 1) * 16384;
            issueA((ks + 1) << 5, nxt);
            issueB((ks + 1) << 5, nxt + 8192);
        }
        v8s af[4], bfr[4];
        #pragma unroll
        for (int mt = 0; mt < 4; ++mt) {
            int row = wm * 64 + mt * 16 + l15;
            af[mt] = *reinterpret_cast<const v8s*>(cur + row * 64 + ((quad * 16) ^ (((row >> 1) & 3) << 4)));
        }
        #pragma unroll
        for (int nt = 0; nt < 4; ++nt) {
            int row = wn * 64 + nt * 16 + l15;
            bfr[nt] = *reinterpret_cast<const v8s*>(cur + 8192 + row * 64 + ((quad * 16) ^ (((row >> 1) & 3) << 4)));
        }
        __builtin_amdgcn_s_setprio(1);
        #pragma unroll
        for (int mt = 0; mt < 4; ++mt)
            #pragma unroll
            for (int nt = 0; nt < 4; ++nt)
                acc[mt * 4 + nt] = mfma16(af[mt], bfr[nt], acc[mt * 4 + nt]);
        __builtin_amdgcn_s_setprio(0);
    }

    #pragma unroll
    for (int mt = 0; mt < 4; ++mt)
        #pragma unroll
        for (int nt = 0; nt < 4; ++nt)
            #pragma unroll
            for (int r = 0; r < 4; ++r) {
                long off = (long)(m0 + wm * 64 + mt * 16 + quad * 4 + r) * ldc + n0 + wn * 64 + nt * 16 + l15;
                if (c32) ((float*)C)[off] = acc[mt * 4 + nt][r];
                else     ((bf16*)C)[off] = f2bf(acc[mt * 4 + nt][r]);
            }
}

// ---------------- generic GEMM: C = A @ Bt^T (64² tile; G1 + G3) ----------------
__global__ __launch_bounds__(256) void gemm_bt(
    const void* __restrict__ A, long lda, long strideA, int aExt,
    const void* __restrict__ Bt, long ldb, long strideB, int bExt,
    void* __restrict__ C, long ldc, long strideC, int cExt,
    int K, const int* __restrict__ gf)
{
    const bool f32 = (*gf == 0);
    const bool a32 = aExt && f32, b32 = bExt && f32, c32 = cExt && f32;
    __shared__ bf16 As[2][64][40];
    __shared__ bf16 Bs[2][64][40];
    const int tid = threadIdx.x;
    const int w = tid >> 6, lane = tid & 63, quad = lane >> 4, l15 = lane & 15;
    const long aoff = (long)blockIdx.z * strideA;
    const long boff = (long)blockIdx.z * strideB;
    const long coff = (long)blockIdx.z * strideC;
    const int m0 = blockIdx.y * 64, n0 = blockIdx.x * 64;
    const int lr = tid >> 2, lc = (tid & 3) * 8;

    v4f acc[4];
    #pragma unroll
    for (int i = 0; i < 4; ++i) acc[i] = vzero();

    v8s av = ld8(A,  aoff + (long)(m0 + lr) * lda + lc, a32);
    v8s bv = ld8(Bt, boff + (long)(n0 + lr) * ldb + lc, b32);

    for (int k0 = 0; k0 < K; k0 += 32) {
        const int bi = (k0 >> 5) & 1;
        *reinterpret_cast<v8s*>(&As[bi][lr][lc]) = av;
        *reinterpret_cast<v8s*>(&Bs[bi][lr][lc]) = bv;
        if (k0 + 32 < K) {
            av = ld8(A,  aoff + (long)(m0 + lr) * lda + k0 + 32 + lc, a32);
            bv = ld8(Bt, boff + (long)(n0 + lr) * ldb + k0 + 32 + lc, b32);
        }
        __syncthreads();
        v8s af = *reinterpret_cast<const v8s*>(&As[bi][w * 16 + l15][quad * 8]);
        #pragma unroll
        for (int nt = 0; nt < 4; ++nt) {
            v8s bfv = *reinterpret_cast<const v8s*>(&Bs[bi][nt * 16 + l15][quad * 8]);
            acc[nt] = mfma16(af, bfv, acc[nt]);
        }
    }
    #pragma unroll
    for (int nt = 0; nt < 4; ++nt)
        #pragma unroll
        for (int r = 0; r < 4; ++r) {
            long off = coff + (long)(m0 + w * 16 + quad * 4 + r) * ldc + n0 + nt * 16 + l15;
            if (c32) ((float*)C)[off] = acc[nt][r];
            else     ((bf16*)C)[off] = f2bf(acc[nt][r]);
        }
}

// ---------------- RMSNorm width 1536 ----
__global__ __launch_bounds__(256) void rmsnorm_q(
    const bf16* __restrict__ in, const void* __restrict__ wt, bf16* __restrict__ out,
    const int* __restrict__ gf)
{
    const bool f32 = (*gf == 0);
    int row = blockIdx.x;
    const bf16* x = in + (long)row * QL_;
    float v[6]; float ss = 0.f;
    #pragma unroll
    for (int i = 0; i < 6; ++i) { v[i] = bf2f(x[threadIdx.x + i * 256]); ss += v[i] * v[i]; }
    #pragma unroll
    for (int off = 1; off < 64; off <<= 1) ss += __shfl_xor(ss, off);
    __shared__ float ws4[4];
    if ((threadIdx.x & 63) == 0) ws4[threadIdx.x >> 6] = ss;
    __syncthreads();
    float rs = rsqrtf((ws4[0] + ws4[1] + ws4[2] + ws4[3]) / (float)QL_ + 1e-6f);
    bf16* o = out + (long)row * QL_;
    #pragma unroll
    for (int i = 0; i < 6; ++i) {
        int c = threadIdx.x + i * 256;
        o[c] = f2bf(v[i] * rs * ld1(wt, c, f32));
    }
}

// ---------------- kv: rmsnorm(512) + rope(64) ----------------
__global__ __launch_bounds__(256) void kv_proc(
    bf16* __restrict__ kvf, const void* __restrict__ wt,
    const void* __restrict__ fcos, const void* __restrict__ fsin,
    const int* __restrict__ gf)
{
    const bool f32 = (*gf == 0);
    int row = blockIdx.x;             // b*2048 + s
    int s = row & (S_ - 1);
    bf16* x = kvf + (long)row * DQK_;
    float v[2]; float ss = 0.f;
    #pragma unroll
    for (int i = 0; i < 2; ++i) { v[i] = bf2f(x[threadIdx.x + i * 256]); ss += v[i] * v[i]; }
    #pragma unroll
    for (int off = 1; off < 64; off <<= 1) ss += __shfl_xor(ss, off);
    __shared__ float ws4[4];
    if ((threadIdx.x & 63) == 0) ws4[threadIdx.x >> 6] = ss;
    __syncthreads();
    float rs = rsqrtf((ws4[0] + ws4[1] + ws4[2] + ws4[3]) / (float)KVL_ + 1e-6f);
    #pragma unroll
    for (int i = 0; i < 2; ++i) {
        int c = threadIdx.x + i * 256;
        x[c] = f2bf(v[i] * rs * ld1(wt, c, f32));
    }
    if (threadIdx.x < 32) {
        int i = threadIdx.x;
        float x0 = bf2f(x[KVL_ + 2 * i]), x1 = bf2f(x[KVL_ + 2 * i + 1]);
        float c = ld1(fcos, s * 32 + i, f32), sn = ld1(fsin, s * 32 + i, f32);
        x[KVL_ + 2 * i]     = f2bf(x0 * c - x1 * sn);
        x[KVL_ + 2 * i + 1] = f2bf(x0 * sn + x1 * c);
    }
}

// ---------------- q pack ----
__global__ __launch_bounds__(512) void q_pack(
    const bf16* __restrict__ qfull, const void* __restrict__ fcos, const void* __restrict__ fsin,
    bf16* __restrict__ qnope, bf16* __restrict__ qpe, const int* __restrict__ gf)
{
    const bool f32 = (*gf == 0);
    int row = blockIdx.x;             // b*2048 + s
    int s = row & (S_ - 1);
    int b = row >> 11;
    const bf16* q = qfull + (long)row * (H_ * QKH_);
    int t = threadIdx.x;
    {   // rope
        int h = t >> 5, i = t & 31;
        float x0 = bf2f(q[h * QKH_ + NOPE_ + 2 * i]);
        float x1 = bf2f(q[h * QKH_ + NOPE_ + 2 * i + 1]);
        float c = ld1(fcos, s * 32 + i, f32), sn = ld1(fsin, s * 32 + i, f32);
        bf16* dst = qpe + ((long)(h * B_ + b) * S_ + s) * ROPE_;
        dst[2 * i]     = f2bf(x0 * c - x1 * sn);
        dst[2 * i + 1] = f2bf(x0 * sn + x1 * c);
    }
    if (t < 256) {  // nope copy
        int h = t >> 4, d0 = (t & 15) * 8;
        v8s v = *reinterpret_cast<const v8s*>(q + h * QKH_ + d0);
        *reinterpret_cast<v8s*>(qnope + ((long)h * 4096 + row) * NOPE_ + d0) = v;
    }
}

// ---------------- V transpose: kvf[:, :512] -> Vt (B, 512, S) ----------------
__global__ __launch_bounds__(256) void v_transpose(
    const bf16* __restrict__ kcomb, bf16* __restrict__ vt)
{
    __shared__ bf16 tile[64][72];
    int b = blockIdx.z, t0 = blockIdx.x * 64, c0 = blockIdx.y * 64;
    int tid = threadIdx.x;
    int r = tid >> 2, sg = tid & 3;
    const bf16* src = kcomb + ((long)b * S_ + t0 + r) * DQK_ + c0 + sg * 16;
    #pragma unroll
    for (int i = 0; i < 2; ++i)
        *reinterpret_cast<v8s*>(&tile[r][sg * 16 + i * 8]) = reinterpret_cast<const v8s*>(src)[i];
    __syncthreads();
    int c = tid >> 2;
    bf16* dst = vt + ((long)b * KVL_ + c0 + c) * S_ + t0 + sg * 16;
    bf16 tmp[16];
    #pragma unroll
    for (int i = 0; i < 16; ++i) tmp[i] = tile[sg * 16 + i][c];
    #pragma unroll
    for (int i = 0; i < 2; ++i)
        reinterpret_cast<v8s*>(dst)[i] = *reinterpret_cast<v8s*>(&tmp[i * 8]);
}

// ---------------- wkv_b nope rows transpose ----------------
__global__ __launch_bounds__(256) void wkvb_t_kernel(
    const void* __restrict__ wkvb, bf16* __restrict__ outp, const int* __restrict__ gf)
{
    const bool f32 = (*gf == 0);
    long idx = (long)blockIdx.x * 256 + threadIdx.x;  // 16*512*128
    int h = (int)(idx >> 16);
    int rem = (int)(idx & 65535);
    int c = rem >> 7, d = rem & 127;
    outp[idx] = f2bf(ld1(wkvb, ((long)(h * 256 + d)) * KVL_ + c, f32));
}

// ---------------- flash attention: 8-wave ctx-split (R4 best: 800-812 us) ----------------
__global__ __launch_bounds__(512, 2) void attn(
    const bf16* __restrict__ qnope, // (H, 4096, 128)
    const bf16* __restrict__ qpe,   // (H*B, S, 64)
    const bf16* __restrict__ kc,    // (B, S, 576)
    const bf16* __restrict__ vt,    // (B, 512, S)
    const bf16* __restrict__ wkvbt, // (H, 512, 128)
    const void* __restrict__ wkvb,  // external (H*256, 512); rows h*256+128.. = wv
    bf16* __restrict__ oheads,      // (4096, 2048), head h at cols h*128..
    const int* __restrict__ gf)
{
    __shared__ bf16 sm[78848];      // 157696 B
    char* smc = (char*)sm;
    const bool e32 = (*gf == 0);
    const int tid = threadIdx.x;
    const int w = tid >> 6, lane = tid & 63, quad = lane >> 4, l15 = lane & 15;
    const int wr = w & 3, wc = w >> 2;
    const int qb = gridDim.x - 1 - blockIdx.x;   // longest blocks first
    const int bh = blockIdx.y;                    // h*B + b
    const int b = bh & (B_ - 1), h = bh >> 1;
    const int q0 = qb * 64;

    // ---- prologue: q_abs = qnope_tile @ wkvbt_h^T -> qreg[18] A-frags
    #pragma unroll
    for (int i = 0; i < 2; ++i) {   // stage Qn (64x128 -> [64][136])
        int a = tid + i * 512, rr = a >> 4, sg = a & 15;
        *reinterpret_cast<v8s*>(&sm[8704 + rr * 136 + sg * 8]) =
            *reinterpret_cast<const v8s*>(qnope + ((long)h * 4096 + b * 2048 + q0 + rr) * NOPE_ + sg * 8);
    }
    v8s qreg[18];
    for (int p = 0; p < 4; ++p) {
        sync_nodrain();
        #pragma unroll
        for (int i = 0; i < 4; ++i) {   // stage Wt: 128 rows (c-dim) x 128 (d-dim)
            int a = tid + i * 512, rr = a >> 4, sg = a & 15;
            *reinterpret_cast<v8s*>(&sm[17408 + rr * 136 + sg * 8]) =
                *reinterpret_cast<const v8s*>(wkvbt + ((long)h * 512 + p * 128 + rr) * NOPE_ + sg * 8);
        }
        sync_nodrain();
        v4f qacc[4];
        #pragma unroll
        for (int i = 0; i < 4; ++i) qacc[i] = vzero();
        #pragma unroll
        for (int kk = 0; kk < 4; ++kk) {
            v8s aq = *reinterpret_cast<const v8s*>(&sm[8704 + (wr * 16 + l15) * 136 + kk * 32 + quad * 8]);
            #pragma unroll
            for (int nt = 0; nt < 4; ++nt) {
                v8s bw = *reinterpret_cast<const v8s*>(&sm[17408 + (wc * 64 + nt * 16 + l15) * 136 + kk * 32 + quad * 8]);
                qacc[nt] = mfma16(aq, bw, qacc[nt]);
            }
        }
        #pragma unroll
        for (int nt = 0; nt < 4; ++nt)
            #pragma unroll
            for (int r = 0; r < 4; ++r)
                sm[(wr * 16 + quad * 4 + r) * 136 + wc * 64 + nt * 16 + l15] = f2bf(qacc[nt][r]);
        sync_nodrain();
        #pragma unroll
        for (int c2 = 0; c2 < 2; ++c2)
            #pragma unroll
            for (int ks = 0; ks < 2; ++ks)
                qreg[p * 4 + c2 * 2 + ks] =
                    *reinterpret_cast<const v8s*>(&sm[(wr * 16 + l15) * 136 + c2 * 64 + ks * 32 + quad * 8]);
    }
    {   // qpe fragments (d 512..575)
        const bf16* qp = qpe + ((long)bh * S_ + q0 + wr * 16 + l15) * ROPE_;
        qreg[16] = *reinterpret_cast<const v8s*>(qp + quad * 8);
        qreg[17] = *reinterpret_cast<const v8s*>(qp + 32 + quad * 8);
    }
    sync_nodrain();   // prologue LDS reads done before K(0) staging lands

    // ---- staging voffsets (pre-swizzled source; linear LDS dest)
    const char* KbB = (const char*)(kc + (long)b * S_ * DQK_);
    const char* VbB = (const char*)(vt + (long)b * KVL_ * S_);
    unsigned srcK[9], srcV[8];
    #pragma unroll
    for (int j = 0; j < 9; ++j) {   // K tile [64][1152B]
        unsigned f = (unsigned)((j * 512 + tid) * 16);
        unsigned row = f / 1152u;
        unsigned col = f - row * 1152u;
        srcK[j] = row * 1152u + (col ^ ((row & 7u) << 4));
    }
    #pragma unroll
    for (int j = 0; j < 8; ++j) {   // V tile [512][128B]
        unsigned f = (unsigned)((j * 512 + tid) * 16);
        unsigned row = f >> 7, col = f & 127u;
        srcV[j] = row * (unsigned)(S_ * 2) + (col ^ ((row & 7u) << 4));
    }
    const unsigned swz = (unsigned)((l15 & 7) << 4);
    bf16* Psw = sm + 69632 + w * 1152;   // wave-private [16][72]
    char* PswB = (char*)Psw;
    const int nkb = qb + 1;

    // issue K(0)
    #pragma unroll
    for (int j = 0; j < 9; ++j)
        gload16(KbB + srcK[j], smc + j * 8192 + w * 1024);

    float m_run[4], l_run[4];
    v4f o[16];
    #pragma unroll
    for (int i = 0; i < 16; ++i) o[i] = vzero();
    #pragma unroll
    for (int r = 0; r < 4; ++r) { m_run[r] = -3e38f; l_run[r] = 0.f; }

    for (int kb = 0; kb < nkb; ++kb) {
        const int t0 = kb * 64;

        BAR_VM(0);   // K(kb) resident; all waves past PV(kb-1)

        // issue V(kb): flies under QK^T + softmax
        {
            const char* vb = VbB + (long)t0 * 2;
            #pragma unroll
            for (int j = 0; j < 8; ++j)
                gload16(vb + srcV[j], smc + 73728 + j * 8192 + w * 1024);
        }

        // ---- QK^T: 72 MFMAs from swizzled K tile (duplicated across wc pair)
        v4f sacc[4];
        #pragma unroll
        for (int i = 0; i < 4; ++i) sacc[i] = vzero();
        const char* kr = smc + (unsigned)(l15 * 1152);
        __builtin_amdgcn_s_setprio(1);
        #pragma unroll
        for (int g = 0; g < 18; ++g) {
            v8s aq = qreg[g];
            unsigned a0 = ((unsigned)(g * 64 + quad * 16)) ^ swz;
            #pragma unroll
            for (int nt = 0; nt < 4; ++nt) {
                v8s bk = *reinterpret_cast<const v8s*>(kr + nt * 18432 + a0);
                sacc[nt] = mfma16(aq, bk, sacc[nt]);
            }
        }
        __builtin_amdgcn_s_setprio(0);

        sync_nodrain();   // all waves done reading K region
        if (kb + 1 < nkb) {   // issue K(kb+1): flies under softmax + PV
            const char* kbn = KbB + (long)(t0 + 64) * 1152;
            #pragma unroll
            for (int j = 0; j < 9; ++j)
                gload16(kbn + srcK[j], smc + j * 8192 + w * 1024);
        }

        // ---- scale + causal mask
        #pragma unroll
        for (int nt = 0; nt < 4; ++nt) {
            int col = t0 + nt * 16 + l15;
            #pragma unroll
            for (int r = 0; r < 4; ++r) {
                int row = q0 + wr * 16 + quad * 4 + r;
                float s = sacc[nt][r] * SCALE_;
                sacc[nt][r] = (col <= row) ? s : -3e38f;
            }
        }
        // ---- online softmax with exact defer-rescale
        float mx[4];
        #pragma unroll
        for (int r = 0; r < 4; ++r) {
            float m = fmaxf(fmaxf(sacc[0][r], sacc[1][r]), fmaxf(sacc[2][r], sacc[3][r]));
            m = fmaxf(m, __shfl_xor(m, 1));
            m = fmaxf(m, __shfl_xor(m, 2));
            m = fmaxf(m, __shfl_xor(m, 4));
            m = fmaxf(m, __shfl_xor(m, 8));
            mx[r] = m;
        }
        int need = (mx[0] > m_run[0]) | (mx[1] > m_run[1]) | (mx[2] > m_run[2]) | (mx[3] > m_run[3]);
        if (__any(need)) {
            float al[4];
            #pragma unroll
            for (int r = 0; r < 4; ++r) {
                float mnew = fmaxf(m_run[r], mx[r]);
                al[r] = exp2f((m_run[r] - mnew) * LOG2E);
                m_run[r] = mnew;
                l_run[r] *= al[r];
            }
            #pragma unroll
            for (int i = 0; i < 16; ++i)
                #pragma unroll
                for (int r = 0; r < 4; ++r) o[i][r] *= al[r];
        }
        float rsum[4] = {0.f, 0.f, 0.f, 0.f};
        #pragma unroll
        for (int nt = 0; nt < 4; ++nt)
            #pragma unroll
            for (int r = 0; r < 4; ++r) {
                float pv = exp2f((sacc[nt][r] - m_run[r]) * LOG2E);
                rsum[r] += pv;
                Psw[(quad * 4 + r) * 72 + nt * 16 + l15] = f2bf(pv);
            }
        #pragma unroll
        for (int r = 0; r < 4; ++r) {
            float t = rsum[r];
            t += __shfl_xor(t, 1);
            t += __shfl_xor(t, 2);
            t += __shfl_xor(t, 4);
            t += __shfl_xor(t, 8);
            l_run[r] += t;
        }

        // ---- V ready? (K(kb+1)'s 9 loads may remain in flight)
        if (kb + 1 < nkb) { BAR_VM(9); } else { BAR_VM(0); }

        // ---- PV: 32 MFMAs from swizzled V tile (wave's ctx half)
        v8s pa0 = *reinterpret_cast<const v8s*>(PswB + l15 * 144 + quad * 16);
        v8s pa1 = *reinterpret_cast<const v8s*>(PswB + l15 * 144 + 64 + quad * 16);
        const char* vr = smc + 73728 + (unsigned)((wc * 256 + l15) * 128);
        __builtin_amdgcn_s_setprio(1);
        #pragma unroll
        for (int ks = 0; ks < 2; ++ks) {
            v8s pa = ks ? pa1 : pa0;
            unsigned a0 = ((unsigned)(ks * 64 + quad * 16)) ^ swz;
            #pragma unroll
            for (int nt = 0; nt < 16; ++nt) {
                v8s bv = *reinterpret_cast<const v8s*>(vr + nt * 2048 + a0);
                o[nt] = mfma16(pa, bv, o[nt]);
            }
        }
        __builtin_amdgcn_s_setprio(0);
    }

    // ---- epilogue: out_h = (o/l) @ wv_h^T; each wave K=256 partial, exact f32 merge
    sync_nodrain();
    float inv[4];
    #pragma unroll
    for (int r = 0; r < 4; ++r) inv[r] = 1.0f / l_run[r];
    // Po @0: [64][520]
    #pragma unroll
    for (int i = 0; i < 16; ++i)
        #pragma unroll
        for (int r = 0; r < 4; ++r)
            sm[(wr * 16 + quad * 4 + r) * 520 + wc * 256 + i * 16 + l15] = f2bf(o[i][r] * inv[r]);
    v4f oacc[8];
    #pragma unroll
    for (int i = 0; i < 8; ++i) oacc[i] = vzero();

    for (int kcc = 0; kcc < 8; ++kcc) {
        sync_nodrain();
        #pragma unroll
        for (int i = 0; i < 2; ++i) {   // stage both wv halves: [2][128][40]
            int a = wr * 64 + lane + i * 256, rr = a >> 2, sg = a & 3;
            *reinterpret_cast<v8s*>(&sm[36864 + wc * 5120 + rr * 40 + sg * 8]) =
                ld8(wkvb, (long)(h * 256 + 128 + rr) * KVL_ + wc * 256 + kcc * 32 + sg * 8, e32);
        }
        sync_nodrain();
        v8s aq = *reinterpret_cast<const v8s*>(&sm[(wr * 16 + l15) * 520 + wc * 256 + kcc * 32 + quad * 8]);
        #pragma unroll
        for (int nt = 0; nt < 8; ++nt) {
            v8s bw = *reinterpret_cast<const v8s*>(&sm[36864 + wc * 5120 + (nt * 16 + l15) * 40 + quad * 8]);
            oacc[nt] = mfma16(aq, bw, oacc[nt]);
        }
    }
    // merge: wc=1 writes f32 partial, wc=0 adds and stores
    float* Mrg = (float*)(smc + 94208);   // [4][16][128]
    if (wc == 1) {
        #pragma unroll
        for (int nt = 0; nt < 8; ++nt)
            #pragma unroll
            for (int r = 0; r < 4; ++r)
                Mrg[wr * 2048 + (quad * 4 + r) * 128 + nt * 16 + l15] = oacc[nt][r];
    }
    sync_nodrain();
    if (wc == 0) {
        #pragma unroll
        for (int nt = 0; nt < 8; ++nt)
            #pragma unroll
            for (int r = 0; r < 4; ++r)
                oheads[(long)(b * S_ + q0 + wr * 16 + quad * 4 + r) * 2048 + h * 128 + nt * 16 + l15] =
                    f2bf(oacc[nt][r] + Mrg[wr * 2048 + (quad * 4 + r) * 128 + nt * 16 + l15]);
    }
}

extern "C" void kernel_launch(void* const* d_in, const int* in_sizes, int n_in,
                              void* d_out, int out_size, void* d_ws, size_t ws_size,
                              hipStream_t stream) {
    const void* x     = d_in[0];
    const void* fcos  = d_in[1];
    const void* fsin  = d_in[2];
    // d_in[3] = mask (causal) — implemented directly
    const void* wq_a  = d_in[4];
    const void* q_ln  = d_in[5];
    const void* wq_b  = d_in[6];
    const void* wkv_a = d_in[7];
    const void* kv_ln = d_in[8];
    const void* wkv_b = d_in[9];
    const void* wo    = d_in[10];

    // workspace (bf16 elems), peak 30,670,864 elems ~= 58.5 MiB
    bf16* W = (bf16*)d_ws;
    bf16* t0     = W;                 // 6,291,456 (dead after GEMM2)
    bf16* qnope  = W;                 // 8,388,608 (written by q_pack, after t0 dead)
    bf16* qpe    = W + 8388608L;      // 4,194,304
    bf16* qfull  = W + 12582912L;     // 12,582,912 (dead after q_pack)
    bf16* oheads = W + 12582912L;     // 8,388,608 (over qfull)
    bf16* kvf    = W + 25165824L;     // 2,359,296
    bf16* vtb    = W + 27525120L;     // 2,097,152
    bf16* wkvbt  = W + 29622272L;     // 1,048,576
    int*  gflag  = (int*)(W + 30670848L);

    detect_k<<<dim3(1), dim3(64), 0, stream>>>((const unsigned*)fcos, gflag);
    wkvb_t_kernel<<<dim3(4096), dim3(256), 0, stream>>>(wkv_b, wkvbt, gflag);

    // GEMM1: t0 = x @ wq_a^T   (4096 x 1536 x 2048)  [64² tile: 1536 blocks, TLP-hidden]
    gemm_bt<<<dim3(24, 64, 1), dim3(256), 0, stream>>>(
        x, 2048L, 0L, 1, wq_a, 2048L, 0L, 1, t0, 1536L, 0L, 0, 2048, gflag);
    rmsnorm_q<<<dim3(4096), dim3(256), 0, stream>>>(t0, q_ln, t0, gflag);

    // GEMM2: qfull = t0 @ wq_b^T  (4096 x 3072 x 1536)  [128² async-split, 768 blocks]
    gemm128<<<dim3(24, 32), dim3(256), 0, stream>>>(
        t0, 1536L, 0, wq_b, 1536L, 1, qfull, 3072L, 0, 1536, gflag);

    // GEMM3: kvf = x @ wkv_a^T  (4096 x 576 x 2048)  [64² tile, N not /128]
    gemm_bt<<<dim3(9, 64, 1), dim3(256), 0, stream>>>(
        x, 2048L, 0L, 1, wkv_a, 2048L, 0L, 1, kvf, 576L, 0L, 0, 2048, gflag);

    q_pack<<<dim3(4096), dim3(512), 0, stream>>>(qfull, fcos, fsin, qnope, qpe, gflag);
    kv_proc<<<dim3(4096), dim3(256), 0, stream>>>(kvf, kv_ln, fcos, fsin, gflag);
    v_transpose<<<dim3(32, 8, 2), dim3(256), 0, stream>>>(kvf, vtb);

    // attention (+ on-the-fly q_abs, + fused per-head out projection) -> oheads
    attn<<<dim3(32, 32), dim3(512), 0, stream>>>(
        qnope, qpe, kvf, vtb, wkvbt, wkv_b, oheads, gflag);

    // GEMM7: out = oheads @ wo^T  (4096 x 2048 x 2048)  [128² async-split, 512 blocks]
    gemm128<<<dim3(16, 32), dim3(256), 0, stream>>>(
        oheads, 2048L, 0, wo, 2048L, 1, d_out, 2048L, 1, 2048, gflag);
}

// Round 9
// 1078.376 us; speedup vs baseline: 1.2315x; 1.1262x over previous
//
#include <hip/hip_runtime.h>
#include <hip/hip_bf16.h>
#include <math.h>

using bf16 = __hip_bfloat16;
typedef short v8s __attribute__((ext_vector_type(8)));
typedef float v4f __attribute__((ext_vector_type(4)));

#define B_ 2
#define S_ 2048
#define DIM_ 2048
#define H_ 16
#define QL_ 1536
#define KVL_ 512
#define NOPE_ 128
#define ROPE_ 64
#define QKH_ 192
#define DQK_ 576
#define LOG2E 1.4426950408889634f
#define SCALE_ 0.07216878364870323f   // 192^-0.5

__device__ __forceinline__ float bf2f(bf16 x){ return __bfloat162float(x); }
__device__ __forceinline__ bf16 f2bf(float x){ return __float2bfloat16(x); }
union bfu { bf16 b; short s; };
__device__ __forceinline__ short f2s(float x){ bfu u; u.b = __float2bfloat16(x); return u.s; }
__device__ __forceinline__ v4f mfma16(v8s a, v8s b, v4f c){
    return __builtin_amdgcn_mfma_f32_16x16x32_bf16(a, b, c, 0, 0, 0);
}
__device__ __forceinline__ v4f vzero(){ v4f z = {0.f,0.f,0.f,0.f}; return z; }

// No-drain block barrier: orders LDS ops (lgkmcnt(0)) but leaves global loads in flight.
__device__ __forceinline__ void sync_nodrain(){
    asm volatile("s_waitcnt lgkmcnt(0)" ::: "memory");
    __builtin_amdgcn_s_barrier();
    asm volatile("" ::: "memory");
}
// Counted-vmcnt barriers (T4): wait for oldest loads only, keep newer ones in flight.
#define BAR_VM(N) do { \
    asm volatile("s_waitcnt vmcnt(" #N ") lgkmcnt(0)" ::: "memory"); \
    __builtin_amdgcn_s_barrier(); \
    asm volatile("" ::: "memory"); \
} while(0)

// async global->LDS, 16B per lane. LDS dest is wave-uniform base (+ lane*16 by HW);
// global src is per-lane (pre-swizzled for bank-conflict-free LDS reads).
__device__ __forceinline__ void gload16(const void* g, void* l){
    __builtin_amdgcn_global_load_lds(
        (const __attribute__((address_space(1))) unsigned int*)g,
        (__attribute__((address_space(3))) unsigned int*)l, 16, 0, 0);
}

// load 8 contiguous elems as bf16 fragment; f32 -> convert
__device__ __forceinline__ v8s ld8(const void* base, long e, bool f32){
    if (f32){
        const float4* p = reinterpret_cast<const float4*>((const float*)base + e);
        float4 a = p[0], b = p[1];
        v8s r;
        r[0]=f2s(a.x); r[1]=f2s(a.y); r[2]=f2s(a.z); r[3]=f2s(a.w);
        r[4]=f2s(b.x); r[5]=f2s(b.y); r[6]=f2s(b.z); r[7]=f2s(b.w);
        return r;
    }
    return *reinterpret_cast<const v8s*>((const bf16*)base + e);
}
__device__ __forceinline__ float ld1(const void* base, long e, bool f32){
    return f32 ? ((const float*)base)[e] : bf2f(((const bf16*)base)[e]);
}

// ---------------- dtype probe ----------------
__global__ void detect_k(const unsigned* fc, int* flag){
    if (threadIdx.x == 0 && blockIdx.x == 0)
        *flag = (*fc == 0x3f800000u) ? 0 : 1;   // 0 = fp32 buffers, 1 = bf16 buffers
}

// ---------------- gemm128 v2: 128x128 tile with ASYNC-SPLIT staging (T14) ----------------
// Loads for step ks+1 ISSUED fire-and-forget after the barrier (f32 -> regs, bf16 ->
// global_load_lds); convert+ds_write at the NEXT iteration's top after one vmcnt(0).
// Latency window = full compute phase. 64-B rows -> swizzle scol = col ^ (((row>>1)&3)<<4).
__global__ __launch_bounds__(256) void gemm128(
    const void* __restrict__ A, long lda, int aExt,
    const void* __restrict__ Bt, long ldb, int bExt,
    void* __restrict__ C, long ldc, int cExt,
    int K, const int* __restrict__ gf)
{
    const bool f32 = (*gf == 0);
    const bool a32 = aExt && f32, b32 = bExt && f32, c32 = cExt && f32;
    __shared__ __align__(16) char smc[32768];
    const int tid = threadIdx.x;
    const int w = tid >> 6, lane = tid & 63, quad = lane >> 4, l15 = lane & 15;
    const int wm = w & 1, wn = w >> 1;
    // bijective XCD swizzle (grid size % 8 == 0 guaranteed by launcher)
    const int nx = gridDim.x;
    const int n = nx * gridDim.y;
    const int lin = blockIdx.y * nx + blockIdx.x;
    const int cpx = n >> 3;
    const int swzb = (lin & 7) * cpx + (lin >> 3);
    const int m0 = (swzb / nx) * 128, n0 = (swzb % nx) * 128;

    // per-thread panel coords: two 16B chunks, swizzled column
    int prow[2], pscol[2];
    #pragma unroll
    for (int j = 0; j < 2; ++j) {
        int f = (j * 256 + tid) * 16;
        prow[j]  = f >> 6;
        pscol[j] = (f & 63) ^ (((prow[j] >> 1) & 3) << 4);
    }

    v4f acc[16];
    #pragma unroll
    for (int i = 0; i < 16; ++i) acc[i] = vzero();
    const int nk = K >> 5;
    float4 RA[4], RB[4];

    auto issueA = [&](int k0, char* panel){
        if (a32) {
            #pragma unroll
            for (int j = 0; j < 2; ++j) {
                const float* p = (const float*)A + (long)(m0 + prow[j]) * lda + k0 + (pscol[j] >> 1);
                RA[j * 2]     = *(const float4*)p;
                RA[j * 2 + 1] = *(const float4*)(p + 4);
            }
        } else {
            #pragma unroll
            for (int j = 0; j < 2; ++j) {
                const char* g = (const char*)A + ((long)(m0 + prow[j]) * lda + k0) * 2 + pscol[j];
                gload16(g, panel + j * 4096 + w * 1024);
            }
        }
    };
    auto issueB = [&](int k0, char* panel){
        if (b32) {
            #pragma unroll
            for (int j = 0; j < 2; ++j) {
                const float* p = (const float*)Bt + (long)(n0 + prow[j]) * ldb + k0 + (pscol[j] >> 1);
                RB[j * 2]     = *(const float4*)p;
                RB[j * 2 + 1] = *(const float4*)(p + 4);
            }
        } else {
            #pragma unroll
            for (int j = 0; j < 2; ++j) {
                const char* g = (const char*)Bt + ((long)(n0 + prow[j]) * ldb + k0) * 2 + pscol[j];
                gload16(g, panel + j * 4096 + w * 1024);
            }
        }
    };
    auto writeA = [&](char* panel){
        if (a32) {
            #pragma unroll
            for (int j = 0; j < 2; ++j) {
                int f = (j * 256 + tid) * 16;
                float4 x = RA[j * 2], y = RA[j * 2 + 1];
                v8s v;
                v[0]=f2s(x.x); v[1]=f2s(x.y); v[2]=f2s(x.z); v[3]=f2s(x.w);
                v[4]=f2s(y.x); v[5]=f2s(y.y); v[6]=f2s(y.z); v[7]=f2s(y.w);
                *reinterpret_cast<v8s*>(panel + f) = v;
            }
        }
    };
    auto writeB = [&](char* panel){
        if (b32) {
            #pragma unroll
            for (int j = 0; j < 2; ++j) {
                int f = (j * 256 + tid) * 16;
                float4 x = RB[j * 2], y = RB[j * 2 + 1];
                v8s v;
                v[0]=f2s(x.x); v[1]=f2s(x.y); v[2]=f2s(x.z); v[3]=f2s(x.w);
                v[4]=f2s(y.x); v[5]=f2s(y.y); v[6]=f2s(y.z); v[7]=f2s(y.w);
                *reinterpret_cast<v8s*>(panel + f) = v;
            }
        }
    };

    issueA(0, smc);
    issueB(0, smc + 8192);

    for (int ks = 0; ks < nk; ++ks) {
        char* cur = smc + (ks & 1) * 16384;
        asm volatile("s_waitcnt vmcnt(0)" ::: "memory");   // L(ks) landed (regs + LDS)
        writeA(cur);
        writeB(cur + 8192);
        sync_nodrain();
        if (ks + 1 < nk) {
            char* nxt = smc + ((ks + 1) & 1) * 16384;
            issueA((ks + 1) << 5, nxt);
            issueB((ks + 1) << 5, nxt + 8192);
        }
        v8s af[4], bfr[4];
        #pragma unroll
        for (int mt = 0; mt < 4; ++mt) {
            int row = wm * 64 + mt * 16 + l15;
            af[mt] = *reinterpret_cast<const v8s*>(cur + row * 64 + ((quad * 16) ^ (((row >> 1) & 3) << 4)));
        }
        #pragma unroll
        for (int nt = 0; nt < 4; ++nt) {
            int row = wn * 64 + nt * 16 + l15;
            bfr[nt] = *reinterpret_cast<const v8s*>(cur + 8192 + row * 64 + ((quad * 16) ^ (((row >> 1) & 3) << 4)));
        }
        __builtin_amdgcn_s_setprio(1);
        #pragma unroll
        for (int mt = 0; mt < 4; ++mt)
            #pragma unroll
            for (int nt = 0; nt < 4; ++nt)
                acc[mt * 4 + nt] = mfma16(af[mt], bfr[nt], acc[mt * 4 + nt]);
        __builtin_amdgcn_s_setprio(0);
    }

    #pragma unroll
    for (int mt = 0; mt < 4; ++mt)
        #pragma unroll
        for (int nt = 0; nt < 4; ++nt)
            #pragma unroll
            for (int r = 0; r < 4; ++r) {
                long off = (long)(m0 + wm * 64 + mt * 16 + quad * 4 + r) * ldc + n0 + wn * 64 + nt * 16 + l15;
                if (c32) ((float*)C)[off] = acc[mt * 4 + nt][r];
                else     ((bf16*)C)[off] = f2bf(acc[mt * 4 + nt][r]);
            }
}

// ---------------- generic GEMM: C = A @ Bt^T (64² tile; G3 only) ----------------
__global__ __launch_bounds__(256) void gemm_bt(
    const void* __restrict__ A, long lda, long strideA, int aExt,
    const void* __restrict__ Bt, long ldb, long strideB, int bExt,
    void* __restrict__ C, long ldc, long strideC, int cExt,
    int K, const int* __restrict__ gf)
{
    const bool f32 = (*gf == 0);
    const bool a32 = aExt && f32, b32 = bExt && f32, c32 = cExt && f32;
    __shared__ bf16 As[2][64][40];
    __shared__ bf16 Bs[2][64][40];
    const int tid = threadIdx.x;
    const int w = tid >> 6, lane = tid & 63, quad = lane >> 4, l15 = lane & 15;
    const long aoff = (long)blockIdx.z * strideA;
    const long boff = (long)blockIdx.z * strideB;
    const long coff = (long)blockIdx.z * strideC;
    const int m0 = blockIdx.y * 64, n0 = blockIdx.x * 64;
    const int lr = tid >> 2, lc = (tid & 3) * 8;

    v4f acc[4];
    #pragma unroll
    for (int i = 0; i < 4; ++i) acc[i] = vzero();

    v8s av = ld8(A,  aoff + (long)(m0 + lr) * lda + lc, a32);
    v8s bv = ld8(Bt, boff + (long)(n0 + lr) * ldb + lc, b32);

    for (int k0 = 0; k0 < K; k0 += 32) {
        const int bi = (k0 >> 5) & 1;
        *reinterpret_cast<v8s*>(&As[bi][lr][lc]) = av;
        *reinterpret_cast<v8s*>(&Bs[bi][lr][lc]) = bv;
        if (k0 + 32 < K) {
            av = ld8(A,  aoff + (long)(m0 + lr) * lda + k0 + 32 + lc, a32);
            bv = ld8(Bt, boff + (long)(n0 + lr) * ldb + k0 + 32 + lc, b32);
        }
        __syncthreads();
        v8s af = *reinterpret_cast<const v8s*>(&As[bi][w * 16 + l15][quad * 8]);
        #pragma unroll
        for (int nt = 0; nt < 4; ++nt) {
            v8s bfv = *reinterpret_cast<const v8s*>(&Bs[bi][nt * 16 + l15][quad * 8]);
            acc[nt] = mfma16(af, bfv, acc[nt]);
        }
    }
    #pragma unroll
    for (int nt = 0; nt < 4; ++nt)
        #pragma unroll
        for (int r = 0; r < 4; ++r) {
            long off = coff + (long)(m0 + w * 16 + quad * 4 + r) * ldc + n0 + nt * 16 + l15;
            if (c32) ((float*)C)[off] = acc[nt][r];
            else     ((bf16*)C)[off] = f2bf(acc[nt][r]);
        }
}

// ---------------- RMSNorm width 1536 ----
__global__ __launch_bounds__(256) void rmsnorm_q(
    const bf16* __restrict__ in, const void* __restrict__ wt, bf16* __restrict__ out,
    const int* __restrict__ gf)
{
    const bool f32 = (*gf == 0);
    int row = blockIdx.x;
    const bf16* x = in + (long)row * QL_;
    float v[6]; float ss = 0.f;
    #pragma unroll
    for (int i = 0; i < 6; ++i) { v[i] = bf2f(x[threadIdx.x + i * 256]); ss += v[i] * v[i]; }
    #pragma unroll
    for (int off = 1; off < 64; off <<= 1) ss += __shfl_xor(ss, off);
    __shared__ float ws4[4];
    if ((threadIdx.x & 63) == 0) ws4[threadIdx.x >> 6] = ss;
    __syncthreads();
    float rs = rsqrtf((ws4[0] + ws4[1] + ws4[2] + ws4[3]) / (float)QL_ + 1e-6f);
    bf16* o = out + (long)row * QL_;
    #pragma unroll
    for (int i = 0; i < 6; ++i) {
        int c = threadIdx.x + i * 256;
        o[c] = f2bf(v[i] * rs * ld1(wt, c, f32));
    }
}

// ---------------- kv: rmsnorm(512) + rope(64) ----------------
__global__ __launch_bounds__(256) void kv_proc(
    bf16* __restrict__ kvf, const void* __restrict__ wt,
    const void* __restrict__ fcos, const void* __restrict__ fsin,
    const int* __restrict__ gf)
{
    const bool f32 = (*gf == 0);
    int row = blockIdx.x;             // b*2048 + s
    int s = row & (S_ - 1);
    bf16* x = kvf + (long)row * DQK_;
    float v[2]; float ss = 0.f;
    #pragma unroll
    for (int i = 0; i < 2; ++i) { v[i] = bf2f(x[threadIdx.x + i * 256]); ss += v[i] * v[i]; }
    #pragma unroll
    for (int off = 1; off < 64; off <<= 1) ss += __shfl_xor(ss, off);
    __shared__ float ws4[4];
    if ((threadIdx.x & 63) == 0) ws4[threadIdx.x >> 6] = ss;
    __syncthreads();
    float rs = rsqrtf((ws4[0] + ws4[1] + ws4[2] + ws4[3]) / (float)KVL_ + 1e-6f);
    #pragma unroll
    for (int i = 0; i < 2; ++i) {
        int c = threadIdx.x + i * 256;
        x[c] = f2bf(v[i] * rs * ld1(wt, c, f32));
    }
    if (threadIdx.x < 32) {
        int i = threadIdx.x;
        float x0 = bf2f(x[KVL_ + 2 * i]), x1 = bf2f(x[KVL_ + 2 * i + 1]);
        float c = ld1(fcos, s * 32 + i, f32), sn = ld1(fsin, s * 32 + i, f32);
        x[KVL_ + 2 * i]     = f2bf(x0 * c - x1 * sn);
        x[KVL_ + 2 * i + 1] = f2bf(x0 * sn + x1 * c);
    }
}

// ---------------- q pack ----
__global__ __launch_bounds__(512) void q_pack(
    const bf16* __restrict__ qfull, const void* __restrict__ fcos, const void* __restrict__ fsin,
    bf16* __restrict__ qnope, bf16* __restrict__ qpe, const int* __restrict__ gf)
{
    const bool f32 = (*gf == 0);
    int row = blockIdx.x;             // b*2048 + s
    int s = row & (S_ - 1);
    int b = row >> 11;
    const bf16* q = qfull + (long)row * (H_ * QKH_);
    int t = threadIdx.x;
    {   // rope
        int h = t >> 5, i = t & 31;
        float x0 = bf2f(q[h * QKH_ + NOPE_ + 2 * i]);
        float x1 = bf2f(q[h * QKH_ + NOPE_ + 2 * i + 1]);
        float c = ld1(fcos, s * 32 + i, f32), sn = ld1(fsin, s * 32 + i, f32);
        bf16* dst = qpe + ((long)(h * B_ + b) * S_ + s) * ROPE_;
        dst[2 * i]     = f2bf(x0 * c - x1 * sn);
        dst[2 * i + 1] = f2bf(x0 * sn + x1 * c);
    }
    if (t < 256) {  // nope copy
        int h = t >> 4, d0 = (t & 15) * 8;
        v8s v = *reinterpret_cast<const v8s*>(q + h * QKH_ + d0);
        *reinterpret_cast<v8s*>(qnope + ((long)h * 4096 + row) * NOPE_ + d0) = v;
    }
}

// ---------------- V transpose: kvf[:, :512] -> Vt (B, 512, S) ----------------
__global__ __launch_bounds__(256) void v_transpose(
    const bf16* __restrict__ kcomb, bf16* __restrict__ vt)
{
    __shared__ bf16 tile[64][72];
    int b = blockIdx.z, t0 = blockIdx.x * 64, c0 = blockIdx.y * 64;
    int tid = threadIdx.x;
    int r = tid >> 2, sg = tid & 3;
    const bf16* src = kcomb + ((long)b * S_ + t0 + r) * DQK_ + c0 + sg * 16;
    #pragma unroll
    for (int i = 0; i < 2; ++i)
        *reinterpret_cast<v8s*>(&tile[r][sg * 16 + i * 8]) = reinterpret_cast<const v8s*>(src)[i];
    __syncthreads();
    int c = tid >> 2;
    bf16* dst = vt + ((long)b * KVL_ + c0 + c) * S_ + t0 + sg * 16;
    bf16 tmp[16];
    #pragma unroll
    for (int i = 0; i < 16; ++i) tmp[i] = tile[sg * 16 + i][c];
    #pragma unroll
    for (int i = 0; i < 2; ++i)
        reinterpret_cast<v8s*>(dst)[i] = *reinterpret_cast<v8s*>(&tmp[i * 8]);
}

// ---------------- wkv_b nope rows transpose ----------------
__global__ __launch_bounds__(256) void wkvb_t_kernel(
    const void* __restrict__ wkvb, bf16* __restrict__ outp, const int* __restrict__ gf)
{
    const bool f32 = (*gf == 0);
    long idx = (long)blockIdx.x * 256 + threadIdx.x;  // 16*512*128
    int h = (int)(idx >> 16);
    int rem = (int)(idx & 65535);
    int c = rem >> 7, d = rem & 127;
    outp[idx] = f2bf(ld1(wkvb, ((long)(h * 256 + d)) * KVL_ + c, f32));
}

// ---------------- flash attention: 8-wave, KEY-SPLIT QK (R9) ----------------
// Waves (wr 0..3, wc 0..1): wr owns 16 q-rows. QK^T: wc owns 32 of 64 keys (NO
// duplication -> QK MFMA/wave 72->36, QK LDS reads 576->288 KB/iter, exp halved).
// PV: wc owns 256 of 512 ctx dims (as R4). P is per-wr SHARED [16][72] (wc writes its
// 32 cols); row-max/sum partials exchanged via MexM/MexS folded into the two existing
// barriers (write-before/read-after) -> same 3 barriers/kb as R4.
// Hazards: MexM rd(kb)->wr(kb+1) separated by BAR_VM(9)+BAR_VM(0); MexS rd(kb)->wr(kb+1)
// by BAR_VM(0)+sync_nodrain; Ps rd(PV,kb)->wr(kb+1) by BAR_VM(0)+sync_nodrain.
// LDS (elems): K 0..36863B | V 36864..69631B... (bytes): K@0 73728 | V@73728 65536 |
// Ps@elem69632 4x[16][72]=4608e | MexM@elem74240 [2][64]f32 | MexS@elem74496 | end 74752e.
__global__ __launch_bounds__(512, 2) void attn(
    const bf16* __restrict__ qnope, // (H, 4096, 128)
    const bf16* __restrict__ qpe,   // (H*B, S, 64)
    const bf16* __restrict__ kc,    // (B, S, 576)
    const bf16* __restrict__ vt,    // (B, 512, S)
    const bf16* __restrict__ wkvbt, // (H, 512, 128)
    const void* __restrict__ wkvb,  // external (H*256, 512); rows h*256+128.. = wv
    bf16* __restrict__ oheads,      // (4096, 2048), head h at cols h*128..
    const int* __restrict__ gf)
{
    __shared__ __align__(16) bf16 sm[78848];      // 157696 B
    char* smc = (char*)sm;
    const bool e32 = (*gf == 0);
    const int tid = threadIdx.x;
    const int w = tid >> 6, lane = tid & 63, quad = lane >> 4, l15 = lane & 15;
    const int wr = w & 3, wc = w >> 2;
    const int qb = gridDim.x - 1 - blockIdx.x;   // longest blocks first
    const int bh = blockIdx.y;                    // h*B + b
    const int b = bh & (B_ - 1), h = bh >> 1;
    const int q0 = qb * 64;

    // ---- prologue: q_abs = qnope_tile @ wkvbt_h^T -> qreg[18] A-frags (unchanged)
    #pragma unroll
    for (int i = 0; i < 2; ++i) {   // stage Qn (64x128 -> [64][136])
        int a = tid + i * 512, rr = a >> 4, sg = a & 15;
        *reinterpret_cast<v8s*>(&sm[8704 + rr * 136 + sg * 8]) =
            *reinterpret_cast<const v8s*>(qnope + ((long)h * 4096 + b * 2048 + q0 + rr) * NOPE_ + sg * 8);
    }
    v8s qreg[18];
    for (int p = 0; p < 4; ++p) {
        sync_nodrain();
        #pragma unroll
        for (int i = 0; i < 4; ++i) {   // stage Wt: 128 rows (c-dim) x 128 (d-dim)
            int a = tid + i * 512, rr = a >> 4, sg = a & 15;
            *reinterpret_cast<v8s*>(&sm[17408 + rr * 136 + sg * 8]) =
                *reinterpret_cast<const v8s*>(wkvbt + ((long)h * 512 + p * 128 + rr) * NOPE_ + sg * 8);
        }
        sync_nodrain();
        v4f qacc[4];
        #pragma unroll
        for (int i = 0; i < 4; ++i) qacc[i] = vzero();
        #pragma unroll
        for (int kk = 0; kk < 4; ++kk) {
            v8s aq = *reinterpret_cast<const v8s*>(&sm[8704 + (wr * 16 + l15) * 136 + kk * 32 + quad * 8]);
            #pragma unroll
            for (int nt = 0; nt < 4; ++nt) {
                v8s bw = *reinterpret_cast<const v8s*>(&sm[17408 + (wc * 64 + nt * 16 + l15) * 136 + kk * 32 + quad * 8]);
                qacc[nt] = mfma16(aq, bw, qacc[nt]);
            }
        }
        #pragma unroll
        for (int nt = 0; nt < 4; ++nt)
            #pragma unroll
            for (int r = 0; r < 4; ++r)
                sm[(wr * 16 + quad * 4 + r) * 136 + wc * 64 + nt * 16 + l15] = f2bf(qacc[nt][r]);
        sync_nodrain();
        #pragma unroll
        for (int c2 = 0; c2 < 2; ++c2)
            #pragma unroll
            for (int ks = 0; ks < 2; ++ks)
                qreg[p * 4 + c2 * 2 + ks] =
                    *reinterpret_cast<const v8s*>(&sm[(wr * 16 + l15) * 136 + c2 * 64 + ks * 32 + quad * 8]);
    }
    {   // qpe fragments (d 512..575)
        const bf16* qp = qpe + ((long)bh * S_ + q0 + wr * 16 + l15) * ROPE_;
        qreg[16] = *reinterpret_cast<const v8s*>(qp + quad * 8);
        qreg[17] = *reinterpret_cast<const v8s*>(qp + 32 + quad * 8);
    }
    sync_nodrain();   // prologue LDS reads done before K(0) staging lands

    // ---- staging voffsets (pre-swizzled source; linear LDS dest)
    const char* KbB = (const char*)(kc + (long)b * S_ * DQK_);
    const char* VbB = (const char*)(vt + (long)b * KVL_ * S_);
    unsigned srcK[9], srcV[8];
    #pragma unroll
    for (int j = 0; j < 9; ++j) {   // K tile [64][1152B]
        unsigned f = (unsigned)((j * 512 + tid) * 16);
        unsigned row = f / 1152u;
        unsigned col = f - row * 1152u;
        srcK[j] = row * 1152u + (col ^ ((row & 7u) << 4));
    }
    #pragma unroll
    for (int j = 0; j < 8; ++j) {   // V tile [512][128B]
        unsigned f = (unsigned)((j * 512 + tid) * 16);
        unsigned row = f >> 7, col = f & 127u;
        srcV[j] = row * (unsigned)(S_ * 2) + (col ^ ((row & 7u) << 4));
    }
    const unsigned swz = (unsigned)((l15 & 7) << 4);
    bf16* Ps_wr = sm + 69632 + wr * 1152;      // per-wr SHARED [16][72]
    char* Ps_wrB = (char*)Ps_wr;
    float* MexM = (float*)(sm + 74240);        // [2][64]
    float* MexS = (float*)(sm + 74496);        // [2][64]
    const int nkb = qb + 1;

    // issue K(0)
    #pragma unroll
    for (int j = 0; j < 9; ++j)
        gload16(KbB + srcK[j], smc + j * 8192 + w * 1024);

    float m_run[4], l_run[4];
    v4f o[16];
    #pragma unroll
    for (int i = 0; i < 16; ++i) o[i] = vzero();
    #pragma unroll
    for (int r = 0; r < 4; ++r) { m_run[r] = -3e38f; l_run[r] = 0.f; }

    for (int kb = 0; kb < nkb; ++kb) {
        const int t0 = kb * 64;

        BAR_VM(0);   // K(kb) resident; all waves past PV(kb-1)

        // issue V(kb): flies under QK^T + softmax
        {
            const char* vb = VbB + (long)t0 * 2;
            #pragma unroll
            for (int j = 0; j < 8; ++j)
                gload16(vb + srcV[j], smc + 73728 + j * 8192 + w * 1024);
        }

        // ---- QK^T: 36 MFMAs, key-split (wave owns keys wc*32..+31)
        v4f sacc[2];
        sacc[0] = vzero(); sacc[1] = vzero();
        const char* kr = smc + (unsigned)(l15 * 1152) + (unsigned)(wc * 2) * 18432u;
        __builtin_amdgcn_s_setprio(1);
        #pragma unroll
        for (int g = 0; g < 18; ++g) {
            v8s aq = qreg[g];
            unsigned a0 = ((unsigned)(g * 64 + quad * 16)) ^ swz;
            sacc[0] = mfma16(aq, *reinterpret_cast<const v8s*>(kr + a0), sacc[0]);
            sacc[1] = mfma16(aq, *reinterpret_cast<const v8s*>(kr + 18432 + a0), sacc[1]);
        }
        __builtin_amdgcn_s_setprio(0);

        // ---- scale + causal mask (wave's 32 keys)
        #pragma unroll
        for (int ntl = 0; ntl < 2; ++ntl) {
            int col = t0 + (wc * 2 + ntl) * 16 + l15;
            #pragma unroll
            for (int r = 0; r < 4; ++r) {
                int row = q0 + wr * 16 + quad * 4 + r;
                float s = sacc[ntl][r] * SCALE_;
                sacc[ntl][r] = (col <= row) ? s : -3e38f;
            }
        }
        // ---- partial row-max over wave's 32 keys -> MexM (before barrier)
        v4f mxv;
        #pragma unroll
        for (int r = 0; r < 4; ++r) {
            float m = fmaxf(sacc[0][r], sacc[1][r]);
            m = fmaxf(m, __shfl_xor(m, 1));
            m = fmaxf(m, __shfl_xor(m, 2));
            m = fmaxf(m, __shfl_xor(m, 4));
            m = fmaxf(m, __shfl_xor(m, 8));
            mxv[r] = m;
        }
        if (l15 == 0) *reinterpret_cast<v4f*>(&MexM[wc * 64 + wr * 16 + quad * 4]) = mxv;

        sync_nodrain();   // K region free + m-exchange visible
        if (kb + 1 < nkb) {   // issue K(kb+1): flies under softmax + PV
            const char* kbn = KbB + (long)(t0 + 64) * 1152;
            #pragma unroll
            for (int j = 0; j < 9; ++j)
                gload16(kbn + srcK[j], smc + j * 8192 + w * 1024);
        }

        // ---- merged max + exact defer-rescale
        v4f ma = *reinterpret_cast<const v4f*>(&MexM[wr * 16 + quad * 4]);
        v4f mb = *reinterpret_cast<const v4f*>(&MexM[64 + wr * 16 + quad * 4]);
        float mfull[4]; int need = 0;
        #pragma unroll
        for (int r = 0; r < 4; ++r) {
            mfull[r] = fmaxf(ma[r], mb[r]);
            need |= (mfull[r] > m_run[r]) ? 1 : 0;
        }
        if (__any(need)) {
            #pragma unroll
            for (int r = 0; r < 4; ++r) {
                float mnew = fmaxf(m_run[r], mfull[r]);
                float al = exp2f((m_run[r] - mnew) * LOG2E);
                m_run[r] = mnew;
                l_run[r] *= al;
                #pragma unroll
                for (int i = 0; i < 16; ++i) o[i][r] *= al;
            }
        }
        // ---- exp + partial row-sum + P write (shared per wr)
        v4f rsv;
        #pragma unroll
        for (int r = 0; r < 4; ++r) rsv[r] = 0.f;
        #pragma unroll
        for (int ntl = 0; ntl < 2; ++ntl)
            #pragma unroll
            for (int r = 0; r < 4; ++r) {
                float pv = exp2f((sacc[ntl][r] - m_run[r]) * LOG2E);
                rsv[r] += pv;
                Ps_wr[(quad * 4 + r) * 72 + (wc * 2 + ntl) * 16 + l15] = f2bf(pv);
            }
        #pragma unroll
        for (int r = 0; r < 4; ++r) {
            float t = rsv[r];
            t += __shfl_xor(t, 1);
            t += __shfl_xor(t, 2);
            t += __shfl_xor(t, 4);
            t += __shfl_xor(t, 8);
            rsv[r] = t;
        }
        if (l15 == 0) *reinterpret_cast<v4f*>(&MexS[wc * 64 + wr * 16 + quad * 4]) = rsv;

        // ---- V ready + s-exchange visible (K(kb+1)'s 9 loads stay in flight)
        if (kb + 1 < nkb) { BAR_VM(9); } else { BAR_VM(0); }
        {
            v4f sa = *reinterpret_cast<const v4f*>(&MexS[wr * 16 + quad * 4]);
            v4f sb = *reinterpret_cast<const v4f*>(&MexS[64 + wr * 16 + quad * 4]);
            #pragma unroll
            for (int r = 0; r < 4; ++r) l_run[r] += sa[r] + sb[r];
        }

        // ---- PV: 32 MFMAs from swizzled V tile (wave's ctx half); P from shared Ps_wr
        v8s pa0 = *reinterpret_cast<const v8s*>(Ps_wrB + l15 * 144 + quad * 16);
        v8s pa1 = *reinterpret_cast<const v8s*>(Ps_wrB + l15 * 144 + 64 + quad * 16);
        const char* vr = smc + 73728 + (unsigned)((wc * 256 + l15) * 128);
        __builtin_amdgcn_s_setprio(1);
        #pragma unroll
        for (int ks = 0; ks < 2; ++ks) {
            v8s pa = ks ? pa1 : pa0;
            unsigned a0 = ((unsigned)(ks * 64 + quad * 16)) ^ swz;
            #pragma unroll
            for (int nt = 0; nt < 16; ++nt) {
                v8s bv = *reinterpret_cast<const v8s*>(vr + nt * 2048 + a0);
                o[nt] = mfma16(pa, bv, o[nt]);
            }
        }
        __builtin_amdgcn_s_setprio(0);
    }

    // ---- epilogue: out_h = (o/l) @ wv_h^T; each wave K=256 partial, exact f32 merge
    sync_nodrain();
    float inv[4];
    #pragma unroll
    for (int r = 0; r < 4; ++r) inv[r] = 1.0f / l_run[r];
    // Po @0: [64][520]
    #pragma unroll
    for (int i = 0; i < 16; ++i)
        #pragma unroll
        for (int r = 0; r < 4; ++r)
            sm[(wr * 16 + quad * 4 + r) * 520 + wc * 256 + i * 16 + l15] = f2bf(o[i][r] * inv[r]);
    v4f oacc[8];
    #pragma unroll
    for (int i = 0; i < 8; ++i) oacc[i] = vzero();

    for (int kcc = 0; kcc < 8; ++kcc) {
        sync_nodrain();
        #pragma unroll
        for (int i = 0; i < 2; ++i) {   // stage both wv halves: [2][128][40]
            int a = wr * 64 + lane + i * 256, rr = a >> 2, sg = a & 3;
            *reinterpret_cast<v8s*>(&sm[36864 + wc * 5120 + rr * 40 + sg * 8]) =
                ld8(wkvb, (long)(h * 256 + 128 + rr) * KVL_ + wc * 256 + kcc * 32 + sg * 8, e32);
        }
        sync_nodrain();
        v8s aq = *reinterpret_cast<const v8s*>(&sm[(wr * 16 + l15) * 520 + wc * 256 + kcc * 32 + quad * 8]);
        #pragma unroll
        for (int nt = 0; nt < 8; ++nt) {
            v8s bw = *reinterpret_cast<const v8s*>(&sm[36864 + wc * 5120 + (nt * 16 + l15) * 40 + quad * 8]);
            oacc[nt] = mfma16(aq, bw, oacc[nt]);
        }
    }
    // merge: wc=1 writes f32 partial, wc=0 adds and stores
    float* Mrg = (float*)(smc + 94208);   // [4][16][128]
    if (wc == 1) {
        #pragma unroll
        for (int nt = 0; nt < 8; ++nt)
            #pragma unroll
            for (int r = 0; r < 4; ++r)
                Mrg[wr * 2048 + (quad * 4 + r) * 128 + nt * 16 + l15] = oacc[nt][r];
    }
    sync_nodrain();
    if (wc == 0) {
        #pragma unroll
        for (int nt = 0; nt < 8; ++nt)
            #pragma unroll
            for (int r = 0; r < 4; ++r)
                oheads[(long)(b * S_ + q0 + wr * 16 + quad * 4 + r) * 2048 + h * 128 + nt * 16 + l15] =
                    f2bf(oacc[nt][r] + Mrg[wr * 2048 + (quad * 4 + r) * 128 + nt * 16 + l15]);
    }
}

extern "C" void kernel_launch(void* const* d_in, const int* in_sizes, int n_in,
                              void* d_out, int out_size, void* d_ws, size_t ws_size,
                              hipStream_t stream) {
    const void* x     = d_in[0];
    const void* fcos  = d_in[1];
    const void* fsin  = d_in[2];
    // d_in[3] = mask (causal) — implemented directly
    const void* wq_a  = d_in[4];
    const void* q_ln  = d_in[5];
    const void* wq_b  = d_in[6];
    const void* wkv_a = d_in[7];
    const void* kv_ln = d_in[8];
    const void* wkv_b = d_in[9];
    const void* wo    = d_in[10];

    // workspace (bf16 elems), peak 30,670,864 elems ~= 58.5 MiB
    bf16* W = (bf16*)d_ws;
    bf16* t0     = W;                 // 6,291,456 (dead after GEMM2)
    bf16* qnope  = W;                 // 8,388,608 (written by q_pack, after t0 dead)
    bf16* qpe    = W + 8388608L;      // 4,194,304
    bf16* qfull  = W + 12582912L;     // 12,582,912 (dead after q_pack)
    bf16* oheads = W + 12582912L;     // 8,388,608 (over qfull)
    bf16* kvf    = W + 25165824L;     // 2,359,296
    bf16* vtb    = W + 27525120L;     // 2,097,152
    bf16* wkvbt  = W + 29622272L;     // 1,048,576
    int*  gflag  = (int*)(W + 30670848L);

    detect_k<<<dim3(1), dim3(64), 0, stream>>>((const unsigned*)fcos, gflag);
    wkvb_t_kernel<<<dim3(4096), dim3(256), 0, stream>>>(wkv_b, wkvbt, gflag);

    // GEMM1: t0 = x @ wq_a^T   (4096 x 1536 x 2048)  [128² async-split, 384 blocks]
    gemm128<<<dim3(12, 32), dim3(256), 0, stream>>>(
        x, 2048L, 1, wq_a, 2048L, 1, t0, 1536L, 0, 2048, gflag);
    rmsnorm_q<<<dim3(4096), dim3(256), 0, stream>>>(t0, q_ln, t0, gflag);

    // GEMM2: qfull = t0 @ wq_b^T  (4096 x 3072 x 1536)  [128² async-split, 768 blocks]
    gemm128<<<dim3(24, 32), dim3(256), 0, stream>>>(
        t0, 1536L, 0, wq_b, 1536L, 1, qfull, 3072L, 0, 1536, gflag);

    // GEMM3: kvf = x @ wkv_a^T  (4096 x 576 x 2048)  [64² tile, N not /128]
    gemm_bt<<<dim3(9, 64, 1), dim3(256), 0, stream>>>(
        x, 2048L, 0L, 1, wkv_a, 2048L, 0L, 1, kvf, 576L, 0L, 0, 2048, gflag);

    q_pack<<<dim3(4096), dim3(512), 0, stream>>>(qfull, fcos, fsin, qnope, qpe, gflag);
    kv_proc<<<dim3(4096), dim3(256), 0, stream>>>(kvf, kv_ln, fcos, fsin, gflag);
    v_transpose<<<dim3(32, 8, 2), dim3(256), 0, stream>>>(kvf, vtb);

    // attention (+ on-the-fly q_abs, + fused per-head out projection) -> oheads
    attn<<<dim3(32, 32), dim3(512), 0, stream>>>(
        qnope, qpe, kvf, vtb, wkvbt, wkv_b, oheads, gflag);

    // GEMM7: out = oheads @ wo^T  (4096 x 2048 x 2048)  [128² async-split, 512 blocks]
    gemm128<<<dim3(16, 32), dim3(256), 0, stream>>>(
        oheads, 2048L, 0, wo, 2048L, 1, d_out, 2048L, 1, 2048, gflag);
}

// Round 10
// 1045.083 us; speedup vs baseline: 1.2708x; 1.0319x over previous
//
#include <hip/hip_runtime.h>
#include <hip/hip_bf16.h>
#include <math.h>

using bf16 = __hip_bfloat16;
typedef short v8s __attribute__((ext_vector_type(8)));
typedef float v4f __attribute__((ext_vector_type(4)));

#define B_ 2
#define S_ 2048
#define DIM_ 2048
#define H_ 16
#define QL_ 1536
#define KVL_ 512
#define NOPE_ 128
#define ROPE_ 64
#define QKH_ 192
#define DQK_ 576
#define LOG2E 1.4426950408889634f
#define SCALE_ 0.07216878364870323f   // 192^-0.5

__device__ __forceinline__ float bf2f(bf16 x){ return __bfloat162float(x); }
__device__ __forceinline__ bf16 f2bf(float x){ return __float2bfloat16(x); }
union bfu { bf16 b; short s; };
__device__ __forceinline__ short f2s(float x){ bfu u; u.b = __float2bfloat16(x); return u.s; }
__device__ __forceinline__ v4f mfma16(v8s a, v8s b, v4f c){
    return __builtin_amdgcn_mfma_f32_16x16x32_bf16(a, b, c, 0, 0, 0);
}
__device__ __forceinline__ v4f vzero(){ v4f z = {0.f,0.f,0.f,0.f}; return z; }

// No-drain block barrier: orders LDS ops (lgkmcnt(0)) but leaves global loads in flight.
__device__ __forceinline__ void sync_nodrain(){
    asm volatile("s_waitcnt lgkmcnt(0)" ::: "memory");
    __builtin_amdgcn_s_barrier();
    asm volatile("" ::: "memory");
}
// Counted-vmcnt barriers (T4): wait for oldest loads only, keep newer ones in flight.
#define BAR_VM(N) do { \
    asm volatile("s_waitcnt vmcnt(" #N ") lgkmcnt(0)" ::: "memory"); \
    __builtin_amdgcn_s_barrier(); \
    asm volatile("" ::: "memory"); \
} while(0)

// async global->LDS, 16B per lane. LDS dest is wave-uniform base (+ lane*16 by HW);
// global src is per-lane (pre-swizzled for bank-conflict-free LDS reads).
__device__ __forceinline__ void gload16(const void* g, void* l){
    __builtin_amdgcn_global_load_lds(
        (const __attribute__((address_space(1))) unsigned int*)g,
        (__attribute__((address_space(3))) unsigned int*)l, 16, 0, 0);
}

// load 8 contiguous elems as bf16 fragment; f32 -> convert
__device__ __forceinline__ v8s ld8(const void* base, long e, bool f32){
    if (f32){
        const float4* p = reinterpret_cast<const float4*>((const float*)base + e);
        float4 a = p[0], b = p[1];
        v8s r;
        r[0]=f2s(a.x); r[1]=f2s(a.y); r[2]=f2s(a.z); r[3]=f2s(a.w);
        r[4]=f2s(b.x); r[5]=f2s(b.y); r[6]=f2s(b.z); r[7]=f2s(b.w);
        return r;
    }
    return *reinterpret_cast<const v8s*>((const bf16*)base + e);
}
__device__ __forceinline__ float ld1(const void* base, long e, bool f32){
    return f32 ? ((const float*)base)[e] : bf2f(((const bf16*)base)[e]);
}

// ---------------- dtype probe ----------------
__global__ void detect_k(const unsigned* fc, int* flag){
    if (threadIdx.x == 0 && blockIdx.x == 0)
        *flag = (*fc == 0x3f800000u) ? 0 : 1;   // 0 = fp32 buffers, 1 = bf16 buffers
}

// ---------------- gemm128 v3: 128x128 tile, BK=64, ASYNC-SPLIT staging ----------------
// R9's BK=32 gave only 16 MFMA/wave (~80 cyc matrix work) per barrier - too thin to
// amortize the per-step vmcnt(0)+barrier. BK=64: barriers halve, compute/phase doubles
// (32 MFMA + 16 ds_read per wave). LDS 64 KB (2 bufs x (A 16KB | B 16KB)) -> 2 blocks/CU.
// Panel row = 128 B -> swizzle mask (row&7)<<4 (bits 4-6, stays in row); 16-lane column
// read = 2 lanes/bank (free). Staging: loads for ks+1 ISSUED fire-and-forget after the
// barrier (f32 -> regs RA/RB 8xfloat4, bf16 -> global_load_lds); convert+ds_write at
// next iteration's top after one vmcnt(0). Regs worst case (G1 both-f32): ~220 < 256.
__global__ __launch_bounds__(256) void gemm128(
    const void* __restrict__ A, long lda, int aExt,
    const void* __restrict__ Bt, long ldb, int bExt,
    void* __restrict__ C, long ldc, int cExt,
    int K, const int* __restrict__ gf)
{
    const bool f32 = (*gf == 0);
    const bool a32 = aExt && f32, b32 = bExt && f32, c32 = cExt && f32;
    __shared__ __align__(16) char smc[65536];
    const int tid = threadIdx.x;
    const int w = tid >> 6, lane = tid & 63, quad = lane >> 4, l15 = lane & 15;
    const int wm = w & 1, wn = w >> 1;
    // bijective XCD swizzle (grid size % 8 == 0 guaranteed by launcher)
    const int nx = gridDim.x;
    const int n = nx * gridDim.y;
    const int lin = blockIdx.y * nx + blockIdx.x;
    const int cpx = n >> 3;
    const int swzb = (lin & 7) * cpx + (lin >> 3);
    const int m0 = (swzb / nx) * 128, n0 = (swzb % nx) * 128;

    // per-thread panel coords: four 16B chunks, swizzled column (panel 128 rows x 128 B)
    int prow[4], pscol[4];
    #pragma unroll
    for (int j = 0; j < 4; ++j) {
        int f = (j * 256 + tid) * 16;
        prow[j]  = f >> 7;
        pscol[j] = (f & 127) ^ ((prow[j] & 7) << 4);
    }

    v4f acc[16];
    #pragma unroll
    for (int i = 0; i < 16; ++i) acc[i] = vzero();
    const int nk = K >> 6;
    float4 RA[8], RB[8];

    auto issueA = [&](int k0, char* panel){
        if (a32) {
            #pragma unroll
            for (int j = 0; j < 4; ++j) {
                const float* p = (const float*)A + (long)(m0 + prow[j]) * lda + k0 + (pscol[j] >> 1);
                RA[j * 2]     = *(const float4*)p;
                RA[j * 2 + 1] = *(const float4*)(p + 4);
            }
        } else {
            #pragma unroll
            for (int j = 0; j < 4; ++j) {
                const char* g = (const char*)A + ((long)(m0 + prow[j]) * lda + k0) * 2 + pscol[j];
                gload16(g, panel + j * 4096 + w * 1024);
            }
        }
    };
    auto issueB = [&](int k0, char* panel){
        if (b32) {
            #pragma unroll
            for (int j = 0; j < 4; ++j) {
                const float* p = (const float*)Bt + (long)(n0 + prow[j]) * ldb + k0 + (pscol[j] >> 1);
                RB[j * 2]     = *(const float4*)p;
                RB[j * 2 + 1] = *(const float4*)(p + 4);
            }
        } else {
            #pragma unroll
            for (int j = 0; j < 4; ++j) {
                const char* g = (const char*)Bt + ((long)(n0 + prow[j]) * ldb + k0) * 2 + pscol[j];
                gload16(g, panel + j * 4096 + w * 1024);
            }
        }
    };
    auto writeA = [&](char* panel){
        if (a32) {
            #pragma unroll
            for (int j = 0; j < 4; ++j) {
                int f = (j * 256 + tid) * 16;
                float4 x = RA[j * 2], y = RA[j * 2 + 1];
                v8s v;
                v[0]=f2s(x.x); v[1]=f2s(x.y); v[2]=f2s(x.z); v[3]=f2s(x.w);
                v[4]=f2s(y.x); v[5]=f2s(y.y); v[6]=f2s(y.z); v[7]=f2s(y.w);
                *reinterpret_cast<v8s*>(panel + f) = v;
            }
        }
    };
    auto writeB = [&](char* panel){
        if (b32) {
            #pragma unroll
            for (int j = 0; j < 4; ++j) {
                int f = (j * 256 + tid) * 16;
                float4 x = RB[j * 2], y = RB[j * 2 + 1];
                v8s v;
                v[0]=f2s(x.x); v[1]=f2s(x.y); v[2]=f2s(x.z); v[3]=f2s(x.w);
                v[4]=f2s(y.x); v[5]=f2s(y.y); v[6]=f2s(y.z); v[7]=f2s(y.w);
                *reinterpret_cast<v8s*>(panel + f) = v;
            }
        }
    };

    issueA(0, smc);
    issueB(0, smc + 16384);

    for (int ks = 0; ks < nk; ++ks) {
        char* cur = smc + (ks & 1) * 32768;
        asm volatile("s_waitcnt vmcnt(0)" ::: "memory");   // L(ks) landed (regs + LDS)
        writeA(cur);
        writeB(cur + 16384);
        sync_nodrain();
        if (ks + 1 < nk) {
            char* nxt = smc + ((ks + 1) & 1) * 32768;
            issueA((ks + 1) << 6, nxt);
            issueB((ks + 1) << 6, nxt + 16384);
        }
        v8s af[8], bfr[8];
        #pragma unroll
        for (int mt = 0; mt < 4; ++mt) {
            int row = wm * 64 + mt * 16 + l15;
            int sw = (row & 7) << 4;
            af[mt * 2]     = *reinterpret_cast<const v8s*>(cur + row * 128 + ((quad * 16) ^ sw));
            af[mt * 2 + 1] = *reinterpret_cast<const v8s*>(cur + row * 128 + ((64 + quad * 16) ^ sw));
        }
        #pragma unroll
        for (int nt = 0; nt < 4; ++nt) {
            int row = wn * 64 + nt * 16 + l15;
            int sw = (row & 7) << 4;
            bfr[nt * 2]     = *reinterpret_cast<const v8s*>(cur + 16384 + row * 128 + ((quad * 16) ^ sw));
            bfr[nt * 2 + 1] = *reinterpret_cast<const v8s*>(cur + 16384 + row * 128 + ((64 + quad * 16) ^ sw));
        }
        __builtin_amdgcn_s_setprio(1);
        #pragma unroll
        for (int ks2 = 0; ks2 < 2; ++ks2)
            #pragma unroll
            for (int mt = 0; mt < 4; ++mt)
                #pragma unroll
                for (int nt = 0; nt < 4; ++nt)
                    acc[mt * 4 + nt] = mfma16(af[mt * 2 + ks2], bfr[nt * 2 + ks2], acc[mt * 4 + nt]);
        __builtin_amdgcn_s_setprio(0);
    }

    #pragma unroll
    for (int mt = 0; mt < 4; ++mt)
        #pragma unroll
        for (int nt = 0; nt < 4; ++nt)
            #pragma unroll
            for (int r = 0; r < 4; ++r) {
                long off = (long)(m0 + wm * 64 + mt * 16 + quad * 4 + r) * ldc + n0 + wn * 64 + nt * 16 + l15;
                if (c32) ((float*)C)[off] = acc[mt * 4 + nt][r];
                else     ((bf16*)C)[off] = f2bf(acc[mt * 4 + nt][r]);
            }
}

// ---------------- generic GEMM: C = A @ Bt^T (64² tile; G3 only) ----------------
__global__ __launch_bounds__(256) void gemm_bt(
    const void* __restrict__ A, long lda, long strideA, int aExt,
    const void* __restrict__ Bt, long ldb, long strideB, int bExt,
    void* __restrict__ C, long ldc, long strideC, int cExt,
    int K, const int* __restrict__ gf)
{
    const bool f32 = (*gf == 0);
    const bool a32 = aExt && f32, b32 = bExt && f32, c32 = cExt && f32;
    __shared__ bf16 As[2][64][40];
    __shared__ bf16 Bs[2][64][40];
    const int tid = threadIdx.x;
    const int w = tid >> 6, lane = tid & 63, quad = lane >> 4, l15 = lane & 15;
    const long aoff = (long)blockIdx.z * strideA;
    const long boff = (long)blockIdx.z * strideB;
    const long coff = (long)blockIdx.z * strideC;
    const int m0 = blockIdx.y * 64, n0 = blockIdx.x * 64;
    const int lr = tid >> 2, lc = (tid & 3) * 8;

    v4f acc[4];
    #pragma unroll
    for (int i = 0; i < 4; ++i) acc[i] = vzero();

    v8s av = ld8(A,  aoff + (long)(m0 + lr) * lda + lc, a32);
    v8s bv = ld8(Bt, boff + (long)(n0 + lr) * ldb + lc, b32);

    for (int k0 = 0; k0 < K; k0 += 32) {
        const int bi = (k0 >> 5) & 1;
        *reinterpret_cast<v8s*>(&As[bi][lr][lc]) = av;
        *reinterpret_cast<v8s*>(&Bs[bi][lr][lc]) = bv;
        if (k0 + 32 < K) {
            av = ld8(A,  aoff + (long)(m0 + lr) * lda + k0 + 32 + lc, a32);
            bv = ld8(Bt, boff + (long)(n0 + lr) * ldb + k0 + 32 + lc, b32);
        }
        __syncthreads();
        v8s af = *reinterpret_cast<const v8s*>(&As[bi][w * 16 + l15][quad * 8]);
        #pragma unroll
        for (int nt = 0; nt < 4; ++nt) {
            v8s bfv = *reinterpret_cast<const v8s*>(&Bs[bi][nt * 16 + l15][quad * 8]);
            acc[nt] = mfma16(af, bfv, acc[nt]);
        }
    }
    #pragma unroll
    for (int nt = 0; nt < 4; ++nt)
        #pragma unroll
        for (int r = 0; r < 4; ++r) {
            long off = coff + (long)(m0 + w * 16 + quad * 4 + r) * ldc + n0 + nt * 16 + l15;
            if (c32) ((float*)C)[off] = acc[nt][r];
            else     ((bf16*)C)[off] = f2bf(acc[nt][r]);
        }
}

// ---------------- RMSNorm width 1536 ----
__global__ __launch_bounds__(256) void rmsnorm_q(
    const bf16* __restrict__ in, const void* __restrict__ wt, bf16* __restrict__ out,
    const int* __restrict__ gf)
{
    const bool f32 = (*gf == 0);
    int row = blockIdx.x;
    const bf16* x = in + (long)row * QL_;
    float v[6]; float ss = 0.f;
    #pragma unroll
    for (int i = 0; i < 6; ++i) { v[i] = bf2f(x[threadIdx.x + i * 256]); ss += v[i] * v[i]; }
    #pragma unroll
    for (int off = 1; off < 64; off <<= 1) ss += __shfl_xor(ss, off);
    __shared__ float ws4[4];
    if ((threadIdx.x & 63) == 0) ws4[threadIdx.x >> 6] = ss;
    __syncthreads();
    float rs = rsqrtf((ws4[0] + ws4[1] + ws4[2] + ws4[3]) / (float)QL_ + 1e-6f);
    bf16* o = out + (long)row * QL_;
    #pragma unroll
    for (int i = 0; i < 6; ++i) {
        int c = threadIdx.x + i * 256;
        o[c] = f2bf(v[i] * rs * ld1(wt, c, f32));
    }
}

// ---------------- kv: rmsnorm(512) + rope(64) ----------------
__global__ __launch_bounds__(256) void kv_proc(
    bf16* __restrict__ kvf, const void* __restrict__ wt,
    const void* __restrict__ fcos, const void* __restrict__ fsin,
    const int* __restrict__ gf)
{
    const bool f32 = (*gf == 0);
    int row = blockIdx.x;             // b*2048 + s
    int s = row & (S_ - 1);
    bf16* x = kvf + (long)row * DQK_;
    float v[2]; float ss = 0.f;
    #pragma unroll
    for (int i = 0; i < 2; ++i) { v[i] = bf2f(x[threadIdx.x + i * 256]); ss += v[i] * v[i]; }
    #pragma unroll
    for (int off = 1; off < 64; off <<= 1) ss += __shfl_xor(ss, off);
    __shared__ float ws4[4];
    if ((threadIdx.x & 63) == 0) ws4[threadIdx.x >> 6] = ss;
    __syncthreads();
    float rs = rsqrtf((ws4[0] + ws4[1] + ws4[2] + ws4[3]) / (float)KVL_ + 1e-6f);
    #pragma unroll
    for (int i = 0; i < 2; ++i) {
        int c = threadIdx.x + i * 256;
        x[c] = f2bf(v[i] * rs * ld1(wt, c, f32));
    }
    if (threadIdx.x < 32) {
        int i = threadIdx.x;
        float x0 = bf2f(x[KVL_ + 2 * i]), x1 = bf2f(x[KVL_ + 2 * i + 1]);
        float c = ld1(fcos, s * 32 + i, f32), sn = ld1(fsin, s * 32 + i, f32);
        x[KVL_ + 2 * i]     = f2bf(x0 * c - x1 * sn);
        x[KVL_ + 2 * i + 1] = f2bf(x0 * sn + x1 * c);
    }
}

// ---------------- q pack ----
__global__ __launch_bounds__(512) void q_pack(
    const bf16* __restrict__ qfull, const void* __restrict__ fcos, const void* __restrict__ fsin,
    bf16* __restrict__ qnope, bf16* __restrict__ qpe, const int* __restrict__ gf)
{
    const bool f32 = (*gf == 0);
    int row = blockIdx.x;             // b*2048 + s
    int s = row & (S_ - 1);
    int b = row >> 11;
    const bf16* q = qfull + (long)row * (H_ * QKH_);
    int t = threadIdx.x;
    {   // rope
        int h = t >> 5, i = t & 31;
        float x0 = bf2f(q[h * QKH_ + NOPE_ + 2 * i]);
        float x1 = bf2f(q[h * QKH_ + NOPE_ + 2 * i + 1]);
        float c = ld1(fcos, s * 32 + i, f32), sn = ld1(fsin, s * 32 + i, f32);
        bf16* dst = qpe + ((long)(h * B_ + b) * S_ + s) * ROPE_;
        dst[2 * i]     = f2bf(x0 * c - x1 * sn);
        dst[2 * i + 1] = f2bf(x0 * sn + x1 * c);
    }
    if (t < 256) {  // nope copy
        int h = t >> 4, d0 = (t & 15) * 8;
        v8s v = *reinterpret_cast<const v8s*>(q + h * QKH_ + d0);
        *reinterpret_cast<v8s*>(qnope + ((long)h * 4096 + row) * NOPE_ + d0) = v;
    }
}

// ---------------- V transpose: kvf[:, :512] -> Vt (B, 512, S) ----------------
__global__ __launch_bounds__(256) void v_transpose(
    const bf16* __restrict__ kcomb, bf16* __restrict__ vt)
{
    __shared__ bf16 tile[64][72];
    int b = blockIdx.z, t0 = blockIdx.x * 64, c0 = blockIdx.y * 64;
    int tid = threadIdx.x;
    int r = tid >> 2, sg = tid & 3;
    const bf16* src = kcomb + ((long)b * S_ + t0 + r) * DQK_ + c0 + sg * 16;
    #pragma unroll
    for (int i = 0; i < 2; ++i)
        *reinterpret_cast<v8s*>(&tile[r][sg * 16 + i * 8]) = reinterpret_cast<const v8s*>(src)[i];
    __syncthreads();
    int c = tid >> 2;
    bf16* dst = vt + ((long)b * KVL_ + c0 + c) * S_ + t0 + sg * 16;
    bf16 tmp[16];
    #pragma unroll
    for (int i = 0; i < 16; ++i) tmp[i] = tile[sg * 16 + i][c];
    #pragma unroll
    for (int i = 0; i < 2; ++i)
        reinterpret_cast<v8s*>(dst)[i] = *reinterpret_cast<v8s*>(&tmp[i * 8]);
}

// ---------------- wkv_b nope rows transpose ----------------
__global__ __launch_bounds__(256) void wkvb_t_kernel(
    const void* __restrict__ wkvb, bf16* __restrict__ outp, const int* __restrict__ gf)
{
    const bool f32 = (*gf == 0);
    long idx = (long)blockIdx.x * 256 + threadIdx.x;  // 16*512*128
    int h = (int)(idx >> 16);
    int rem = (int)(idx & 65535);
    int c = rem >> 7, d = rem & 127;
    outp[idx] = f2bf(ld1(wkvb, ((long)(h * 256 + d)) * KVL_ + c, f32));
}

// ---------------- flash attention: 8-wave, KEY-SPLIT QK (R9 best: 652 us) ----------------
// Waves (wr 0..3, wc 0..1): wr owns 16 q-rows. QK^T: wc owns 32 of 64 keys (no
// duplication). PV: wc owns 256 of 512 ctx dims. P per-wr SHARED [16][72]; row-max/sum
// partials exchanged via MexM/MexS folded into the existing 3 barriers/kb.
__global__ __launch_bounds__(512, 2) void attn(
    const bf16* __restrict__ qnope, // (H, 4096, 128)
    const bf16* __restrict__ qpe,   // (H*B, S, 64)
    const bf16* __restrict__ kc,    // (B, S, 576)
    const bf16* __restrict__ vt,    // (B, 512, S)
    const bf16* __restrict__ wkvbt, // (H, 512, 128)
    const void* __restrict__ wkvb,  // external (H*256, 512); rows h*256+128.. = wv
    bf16* __restrict__ oheads,      // (4096, 2048), head h at cols h*128..
    const int* __restrict__ gf)
{
    __shared__ __align__(16) bf16 sm[78848];      // 157696 B
    char* smc = (char*)sm;
    const bool e32 = (*gf == 0);
    const int tid = threadIdx.x;
    const int w = tid >> 6, lane = tid & 63, quad = lane >> 4, l15 = lane & 15;
    const int wr = w & 3, wc = w >> 2;
    const int qb = gridDim.x - 1 - blockIdx.x;   // longest blocks first
    const int bh = blockIdx.y;                    // h*B + b
    const int b = bh & (B_ - 1), h = bh >> 1;
    const int q0 = qb * 64;

    // ---- prologue: q_abs = qnope_tile @ wkvbt_h^T -> qreg[18] A-frags
    #pragma unroll
    for (int i = 0; i < 2; ++i) {   // stage Qn (64x128 -> [64][136])
        int a = tid + i * 512, rr = a >> 4, sg = a & 15;
        *reinterpret_cast<v8s*>(&sm[8704 + rr * 136 + sg * 8]) =
            *reinterpret_cast<const v8s*>(qnope + ((long)h * 4096 + b * 2048 + q0 + rr) * NOPE_ + sg * 8);
    }
    v8s qreg[18];
    for (int p = 0; p < 4; ++p) {
        sync_nodrain();
        #pragma unroll
        for (int i = 0; i < 4; ++i) {   // stage Wt: 128 rows (c-dim) x 128 (d-dim)
            int a = tid + i * 512, rr = a >> 4, sg = a & 15;
            *reinterpret_cast<v8s*>(&sm[17408 + rr * 136 + sg * 8]) =
                *reinterpret_cast<const v8s*>(wkvbt + ((long)h * 512 + p * 128 + rr) * NOPE_ + sg * 8);
        }
        sync_nodrain();
        v4f qacc[4];
        #pragma unroll
        for (int i = 0; i < 4; ++i) qacc[i] = vzero();
        #pragma unroll
        for (int kk = 0; kk < 4; ++kk) {
            v8s aq = *reinterpret_cast<const v8s*>(&sm[8704 + (wr * 16 + l15) * 136 + kk * 32 + quad * 8]);
            #pragma unroll
            for (int nt = 0; nt < 4; ++nt) {
                v8s bw = *reinterpret_cast<const v8s*>(&sm[17408 + (wc * 64 + nt * 16 + l15) * 136 + kk * 32 + quad * 8]);
                qacc[nt] = mfma16(aq, bw, qacc[nt]);
            }
        }
        #pragma unroll
        for (int nt = 0; nt < 4; ++nt)
            #pragma unroll
            for (int r = 0; r < 4; ++r)
                sm[(wr * 16 + quad * 4 + r) * 136 + wc * 64 + nt * 16 + l15] = f2bf(qacc[nt][r]);
        sync_nodrain();
        #pragma unroll
        for (int c2 = 0; c2 < 2; ++c2)
            #pragma unroll
            for (int ks = 0; ks < 2; ++ks)
                qreg[p * 4 + c2 * 2 + ks] =
                    *reinterpret_cast<const v8s*>(&sm[(wr * 16 + l15) * 136 + c2 * 64 + ks * 32 + quad * 8]);
    }
    {   // qpe fragments (d 512..575)
        const bf16* qp = qpe + ((long)bh * S_ + q0 + wr * 16 + l15) * ROPE_;
        qreg[16] = *reinterpret_cast<const v8s*>(qp + quad * 8);
        qreg[17] = *reinterpret_cast<const v8s*>(qp + 32 + quad * 8);
    }
    sync_nodrain();   // prologue LDS reads done before K(0) staging lands

    // ---- staging voffsets (pre-swizzled source; linear LDS dest)
    const char* KbB = (const char*)(kc + (long)b * S_ * DQK_);
    const char* VbB = (const char*)(vt + (long)b * KVL_ * S_);
    unsigned srcK[9], srcV[8];
    #pragma unroll
    for (int j = 0; j < 9; ++j) {   // K tile [64][1152B]
        unsigned f = (unsigned)((j * 512 + tid) * 16);
        unsigned row = f / 1152u;
        unsigned col = f - row * 1152u;
        srcK[j] = row * 1152u + (col ^ ((row & 7u) << 4));
    }
    #pragma unroll
    for (int j = 0; j < 8; ++j) {   // V tile [512][128B]
        unsigned f = (unsigned)((j * 512 + tid) * 16);
        unsigned row = f >> 7, col = f & 127u;
        srcV[j] = row * (unsigned)(S_ * 2) + (col ^ ((row & 7u) << 4));
    }
    const unsigned swz = (unsigned)((l15 & 7) << 4);
    bf16* Ps_wr = sm + 69632 + wr * 1152;      // per-wr SHARED [16][72]
    char* Ps_wrB = (char*)Ps_wr;
    float* MexM = (float*)(sm + 74240);        // [2][64]
    float* MexS = (float*)(sm + 74496);        // [2][64]
    const int nkb = qb + 1;

    // issue K(0)
    #pragma unroll
    for (int j = 0; j < 9; ++j)
        gload16(KbB + srcK[j], smc + j * 8192 + w * 1024);

    float m_run[4], l_run[4];
    v4f o[16];
    #pragma unroll
    for (int i = 0; i < 16; ++i) o[i] = vzero();
    #pragma unroll
    for (int r = 0; r < 4; ++r) { m_run[r] = -3e38f; l_run[r] = 0.f; }

    for (int kb = 0; kb < nkb; ++kb) {
        const int t0 = kb * 64;

        BAR_VM(0);   // K(kb) resident; all waves past PV(kb-1)

        // issue V(kb): flies under QK^T + softmax
        {
            const char* vb = VbB + (long)t0 * 2;
            #pragma unroll
            for (int j = 0; j < 8; ++j)
                gload16(vb + srcV[j], smc + 73728 + j * 8192 + w * 1024);
        }

        // ---- QK^T: 36 MFMAs, key-split (wave owns keys wc*32..+31)
        v4f sacc[2];
        sacc[0] = vzero(); sacc[1] = vzero();
        const char* kr = smc + (unsigned)(l15 * 1152) + (unsigned)(wc * 2) * 18432u;
        __builtin_amdgcn_s_setprio(1);
        #pragma unroll
        for (int g = 0; g < 18; ++g) {
            v8s aq = qreg[g];
            unsigned a0 = ((unsigned)(g * 64 + quad * 16)) ^ swz;
            sacc[0] = mfma16(aq, *reinterpret_cast<const v8s*>(kr + a0), sacc[0]);
            sacc[1] = mfma16(aq, *reinterpret_cast<const v8s*>(kr + 18432 + a0), sacc[1]);
        }
        __builtin_amdgcn_s_setprio(0);

        // ---- scale + causal mask (wave's 32 keys)
        #pragma unroll
        for (int ntl = 0; ntl < 2; ++ntl) {
            int col = t0 + (wc * 2 + ntl) * 16 + l15;
            #pragma unroll
            for (int r = 0; r < 4; ++r) {
                int row = q0 + wr * 16 + quad * 4 + r;
                float s = sacc[ntl][r] * SCALE_;
                sacc[ntl][r] = (col <= row) ? s : -3e38f;
            }
        }
        // ---- partial row-max over wave's 32 keys -> MexM (before barrier)
        v4f mxv;
        #pragma unroll
        for (int r = 0; r < 4; ++r) {
            float m = fmaxf(sacc[0][r], sacc[1][r]);
            m = fmaxf(m, __shfl_xor(m, 1));
            m = fmaxf(m, __shfl_xor(m, 2));
            m = fmaxf(m, __shfl_xor(m, 4));
            m = fmaxf(m, __shfl_xor(m, 8));
            mxv[r] = m;
        }
        if (l15 == 0) *reinterpret_cast<v4f*>(&MexM[wc * 64 + wr * 16 + quad * 4]) = mxv;

        sync_nodrain();   // K region free + m-exchange visible
        if (kb + 1 < nkb) {   // issue K(kb+1): flies under softmax + PV
            const char* kbn = KbB + (long)(t0 + 64) * 1152;
            #pragma unroll
            for (int j = 0; j < 9; ++j)
                gload16(kbn + srcK[j], smc + j * 8192 + w * 1024);
        }

        // ---- merged max + exact defer-rescale
        v4f ma = *reinterpret_cast<const v4f*>(&MexM[wr * 16 + quad * 4]);
        v4f mb = *reinterpret_cast<const v4f*>(&MexM[64 + wr * 16 + quad * 4]);
        float mfull[4]; int need = 0;
        #pragma unroll
        for (int r = 0; r < 4; ++r) {
            mfull[r] = fmaxf(ma[r], mb[r]);
            need |= (mfull[r] > m_run[r]) ? 1 : 0;
        }
        if (__any(need)) {
            #pragma unroll
            for (int r = 0; r < 4; ++r) {
                float mnew = fmaxf(m_run[r], mfull[r]);
                float al = exp2f((m_run[r] - mnew) * LOG2E);
                m_run[r] = mnew;
                l_run[r] *= al;
                #pragma unroll
                for (int i = 0; i < 16; ++i) o[i][r] *= al;
            }
        }
        // ---- exp + partial row-sum + P write (shared per wr)
        v4f rsv;
        #pragma unroll
        for (int r = 0; r < 4; ++r) rsv[r] = 0.f;
        #pragma unroll
        for (int ntl = 0; ntl < 2; ++ntl)
            #pragma unroll
            for (int r = 0; r < 4; ++r) {
                float pv = exp2f((sacc[ntl][r] - m_run[r]) * LOG2E);
                rsv[r] += pv;
                Ps_wr[(quad * 4 + r) * 72 + (wc * 2 + ntl) * 16 + l15] = f2bf(pv);
            }
        #pragma unroll
        for (int r = 0; r < 4; ++r) {
            float t = rsv[r];
            t += __shfl_xor(t, 1);
            t += __shfl_xor(t, 2);
            t += __shfl_xor(t, 4);
            t += __shfl_xor(t, 8);
            rsv[r] = t;
        }
        if (l15 == 0) *reinterpret_cast<v4f*>(&MexS[wc * 64 + wr * 16 + quad * 4]) = rsv;

        // ---- V ready + s-exchange visible (K(kb+1)'s 9 loads stay in flight)
        if (kb + 1 < nkb) { BAR_VM(9); } else { BAR_VM(0); }
        {
            v4f sa = *reinterpret_cast<const v4f*>(&MexS[wr * 16 + quad * 4]);
            v4f sb = *reinterpret_cast<const v4f*>(&MexS[64 + wr * 16 + quad * 4]);
            #pragma unroll
            for (int r = 0; r < 4; ++r) l_run[r] += sa[r] + sb[r];
        }

        // ---- PV: 32 MFMAs from swizzled V tile (wave's ctx half); P from shared Ps_wr
        v8s pa0 = *reinterpret_cast<const v8s*>(Ps_wrB + l15 * 144 + quad * 16);
        v8s pa1 = *reinterpret_cast<const v8s*>(Ps_wrB + l15 * 144 + 64 + quad * 16);
        const char* vr = smc + 73728 + (unsigned)((wc * 256 + l15) * 128);
        __builtin_amdgcn_s_setprio(1);
        #pragma unroll
        for (int ks = 0; ks < 2; ++ks) {
            v8s pa = ks ? pa1 : pa0;
            unsigned a0 = ((unsigned)(ks * 64 + quad * 16)) ^ swz;
            #pragma unroll
            for (int nt = 0; nt < 16; ++nt) {
                v8s bv = *reinterpret_cast<const v8s*>(vr + nt * 2048 + a0);
                o[nt] = mfma16(pa, bv, o[nt]);
            }
        }
        __builtin_amdgcn_s_setprio(0);
    }

    // ---- epilogue: out_h = (o/l) @ wv_h^T; each wave K=256 partial, exact f32 merge
    sync_nodrain();
    float inv[4];
    #pragma unroll
    for (int r = 0; r < 4; ++r) inv[r] = 1.0f / l_run[r];
    // Po @0: [64][520]
    #pragma unroll
    for (int i = 0; i < 16; ++i)
        #pragma unroll
        for (int r = 0; r < 4; ++r)
            sm[(wr * 16 + quad * 4 + r) * 520 + wc * 256 + i * 16 + l15] = f2bf(o[i][r] * inv[r]);
    v4f oacc[8];
    #pragma unroll
    for (int i = 0; i < 8; ++i) oacc[i] = vzero();

    for (int kcc = 0; kcc < 8; ++kcc) {
        sync_nodrain();
        #pragma unroll
        for (int i = 0; i < 2; ++i) {   // stage both wv halves: [2][128][40]
            int a = wr * 64 + lane + i * 256, rr = a >> 2, sg = a & 3;
            *reinterpret_cast<v8s*>(&sm[36864 + wc * 5120 + rr * 40 + sg * 8]) =
                ld8(wkvb, (long)(h * 256 + 128 + rr) * KVL_ + wc * 256 + kcc * 32 + sg * 8, e32);
        }
        sync_nodrain();
        v8s aq = *reinterpret_cast<const v8s*>(&sm[(wr * 16 + l15) * 520 + wc * 256 + kcc * 32 + quad * 8]);
        #pragma unroll
        for (int nt = 0; nt < 8; ++nt) {
            v8s bw = *reinterpret_cast<const v8s*>(&sm[36864 + wc * 5120 + (nt * 16 + l15) * 40 + quad * 8]);
            oacc[nt] = mfma16(aq, bw, oacc[nt]);
        }
    }
    // merge: wc=1 writes f32 partial, wc=0 adds and stores
    float* Mrg = (float*)(smc + 94208);   // [4][16][128]
    if (wc == 1) {
        #pragma unroll
        for (int nt = 0; nt < 8; ++nt)
            #pragma unroll
            for (int r = 0; r < 4; ++r)
                Mrg[wr * 2048 + (quad * 4 + r) * 128 + nt * 16 + l15] = oacc[nt][r];
    }
    sync_nodrain();
    if (wc == 0) {
        #pragma unroll
        for (int nt = 0; nt < 8; ++nt)
            #pragma unroll
            for (int r = 0; r < 4; ++r)
                oheads[(long)(b * S_ + q0 + wr * 16 + quad * 4 + r) * 2048 + h * 128 + nt * 16 + l15] =
                    f2bf(oacc[nt][r] + Mrg[wr * 2048 + (quad * 4 + r) * 128 + nt * 16 + l15]);
    }
}

extern "C" void kernel_launch(void* const* d_in, const int* in_sizes, int n_in,
                              void* d_out, int out_size, void* d_ws, size_t ws_size,
                              hipStream_t stream) {
    const void* x     = d_in[0];
    const void* fcos  = d_in[1];
    const void* fsin  = d_in[2];
    // d_in[3] = mask (causal) — implemented directly
    const void* wq_a  = d_in[4];
    const void* q_ln  = d_in[5];
    const void* wq_b  = d_in[6];
    const void* wkv_a = d_in[7];
    const void* kv_ln = d_in[8];
    const void* wkv_b = d_in[9];
    const void* wo    = d_in[10];

    // workspace (bf16 elems), peak 30,670,864 elems ~= 58.5 MiB
    bf16* W = (bf16*)d_ws;
    bf16* t0     = W;                 // 6,291,456 (dead after GEMM2)
    bf16* qnope  = W;                 // 8,388,608 (written by q_pack, after t0 dead)
    bf16* qpe    = W + 8388608L;      // 4,194,304
    bf16* qfull  = W + 12582912L;     // 12,582,912 (dead after q_pack)
    bf16* oheads = W + 12582912L;     // 8,388,608 (over qfull)
    bf16* kvf    = W + 25165824L;     // 2,359,296
    bf16* vtb    = W + 27525120L;     // 2,097,152
    bf16* wkvbt  = W + 29622272L;     // 1,048,576
    int*  gflag  = (int*)(W + 30670848L);

    detect_k<<<dim3(1), dim3(64), 0, stream>>>((const unsigned*)fcos, gflag);
    wkvb_t_kernel<<<dim3(4096), dim3(256), 0, stream>>>(wkv_b, wkvbt, gflag);

    // GEMM1: t0 = x @ wq_a^T   (4096 x 1536 x 2048)  [128², BK=64, 384 blocks]
    gemm128<<<dim3(12, 32), dim3(256), 0, stream>>>(
        x, 2048L, 1, wq_a, 2048L, 1, t0, 1536L, 0, 2048, gflag);
    rmsnorm_q<<<dim3(4096), dim3(256), 0, stream>>>(t0, q_ln, t0, gflag);

    // GEMM2: qfull = t0 @ wq_b^T  (4096 x 3072 x 1536)  [128², BK=64, 768 blocks]
    gemm128<<<dim3(24, 32), dim3(256), 0, stream>>>(
        t0, 1536L, 0, wq_b, 1536L, 1, qfull, 3072L, 0, 1536, gflag);

    // GEMM3: kvf = x @ wkv_a^T  (4096 x 576 x 2048)  [64² tile, N not /128]
    gemm_bt<<<dim3(9, 64, 1), dim3(256), 0, stream>>>(
        x, 2048L, 0L, 1, wkv_a, 2048L, 0L, 1, kvf, 576L, 0L, 0, 2048, gflag);

    q_pack<<<dim3(4096), dim3(512), 0, stream>>>(qfull, fcos, fsin, qnope, qpe, gflag);
    kv_proc<<<dim3(4096), dim3(256), 0, stream>>>(kvf, kv_ln, fcos, fsin, gflag);
    v_transpose<<<dim3(32, 8, 2), dim3(256), 0, stream>>>(kvf, vtb);

    // attention (+ on-the-fly q_abs, + fused per-head out projection) -> oheads
    attn<<<dim3(32, 32), dim3(512), 0, stream>>>(
        qnope, qpe, kvf, vtb, wkvbt, wkv_b, oheads, gflag);

    // GEMM7: out = oheads @ wo^T  (4096 x 2048 x 2048)  [128², BK=64, 512 blocks]
    gemm128<<<dim3(16, 32), dim3(256), 0, stream>>>(
        oheads, 2048L, 0, wo, 2048L, 1, d_out, 2048L, 1, 2048, gflag);
}

// Round 11
// 848.746 us; speedup vs baseline: 1.5647x; 1.2313x over previous
//
#include <hip/hip_runtime.h>
#include <hip/hip_bf16.h>
#include <math.h>

using bf16 = __hip_bfloat16;
typedef short v8s __attribute__((ext_vector_type(8)));
typedef float v4f __attribute__((ext_vector_type(4)));

#define B_ 2
#define S_ 2048
#define DIM_ 2048
#define H_ 16
#define QL_ 1536
#define KVL_ 512
#define NOPE_ 128
#define ROPE_ 64
#define QKH_ 192
#define DQK_ 576
#define LOG2E 1.4426950408889634f
#define SCALE_ 0.07216878364870323f   // 192^-0.5

__device__ __forceinline__ float bf2f(bf16 x){ return __bfloat162float(x); }
__device__ __forceinline__ bf16 f2bf(float x){ return __float2bfloat16(x); }
union bfu { bf16 b; short s; };
__device__ __forceinline__ short f2s(float x){ bfu u; u.b = __float2bfloat16(x); return u.s; }
__device__ __forceinline__ v4f mfma16(v8s a, v8s b, v4f c){
    return __builtin_amdgcn_mfma_f32_16x16x32_bf16(a, b, c, 0, 0, 0);
}
__device__ __forceinline__ v4f vzero(){ v4f z = {0.f,0.f,0.f,0.f}; return z; }

// No-drain block barrier: orders LDS ops (lgkmcnt(0)) but leaves global loads in flight.
__device__ __forceinline__ void sync_nodrain(){
    asm volatile("s_waitcnt lgkmcnt(0)" ::: "memory");
    __builtin_amdgcn_s_barrier();
    asm volatile("" ::: "memory");
}
// Counted-vmcnt barriers (T4): wait for oldest loads only, keep newer ones in flight.
#define BAR_VM(N) do { \
    asm volatile("s_waitcnt vmcnt(" #N ") lgkmcnt(0)" ::: "memory"); \
    __builtin_amdgcn_s_barrier(); \
    asm volatile("" ::: "memory"); \
} while(0)

// async global->LDS, 16B per lane. LDS dest is wave-uniform base (+ lane*16 by HW);
// global src is per-lane (pre-swizzled for bank-conflict-free LDS reads).
__device__ __forceinline__ void gload16(const void* g, void* l){
    __builtin_amdgcn_global_load_lds(
        (const __attribute__((address_space(1))) unsigned int*)g,
        (__attribute__((address_space(3))) unsigned int*)l, 16, 0, 0);
}

// load 8 contiguous elems as bf16 fragment; f32 -> convert
__device__ __forceinline__ v8s ld8(const void* base, long e, bool f32){
    if (f32){
        const float4* p = reinterpret_cast<const float4*>((const float*)base + e);
        float4 a = p[0], b = p[1];
        v8s r;
        r[0]=f2s(a.x); r[1]=f2s(a.y); r[2]=f2s(a.z); r[3]=f2s(a.w);
        r[4]=f2s(b.x); r[5]=f2s(b.y); r[6]=f2s(b.z); r[7]=f2s(b.w);
        return r;
    }
    return *reinterpret_cast<const v8s*>((const bf16*)base + e);
}
__device__ __forceinline__ float ld1(const void* base, long e, bool f32){
    return f32 ? ((const float*)base)[e] : bf2f(((const bf16*)base)[e]);
}

// ---------------- dtype probe ----------------
__global__ void detect_k(const unsigned* fc, int* flag){
    if (threadIdx.x == 0 && blockIdx.x == 0)
        *flag = (*fc == 0x3f800000u) ? 0 : 1;   // 0 = fp32 buffers, 1 = bf16 buffers
}

// ---------------- gemm128 v3: 128x128 tile, BK=64, ASYNC-SPLIT staging ----------------
__global__ __launch_bounds__(256) void gemm128(
    const void* __restrict__ A, long lda, int aExt,
    const void* __restrict__ Bt, long ldb, int bExt,
    void* __restrict__ C, long ldc, int cExt,
    int K, const int* __restrict__ gf)
{
    const bool f32 = (*gf == 0);
    const bool a32 = aExt && f32, b32 = bExt && f32, c32 = cExt && f32;
    __shared__ __align__(16) char smc[65536];
    const int tid = threadIdx.x;
    const int w = tid >> 6, lane = tid & 63, quad = lane >> 4, l15 = lane & 15;
    const int wm = w & 1, wn = w >> 1;
    // bijective XCD swizzle (grid size % 8 == 0 guaranteed by launcher)
    const int nx = gridDim.x;
    const int n = nx * gridDim.y;
    const int lin = blockIdx.y * nx + blockIdx.x;
    const int cpx = n >> 3;
    const int swzb = (lin & 7) * cpx + (lin >> 3);
    const int m0 = (swzb / nx) * 128, n0 = (swzb % nx) * 128;

    // per-thread panel coords: four 16B chunks, swizzled column (panel 128 rows x 128 B)
    int prow[4], pscol[4];
    #pragma unroll
    for (int j = 0; j < 4; ++j) {
        int f = (j * 256 + tid) * 16;
        prow[j]  = f >> 7;
        pscol[j] = (f & 127) ^ ((prow[j] & 7) << 4);
    }

    v4f acc[16];
    #pragma unroll
    for (int i = 0; i < 16; ++i) acc[i] = vzero();
    const int nk = K >> 6;
    float4 RA[8], RB[8];

    auto issueA = [&](int k0, char* panel){
        if (a32) {
            #pragma unroll
            for (int j = 0; j < 4; ++j) {
                const float* p = (const float*)A + (long)(m0 + prow[j]) * lda + k0 + (pscol[j] >> 1);
                RA[j * 2]     = *(const float4*)p;
                RA[j * 2 + 1] = *(const float4*)(p + 4);
            }
        } else {
            #pragma unroll
            for (int j = 0; j < 4; ++j) {
                const char* g = (const char*)A + ((long)(m0 + prow[j]) * lda + k0) * 2 + pscol[j];
                gload16(g, panel + j * 4096 + w * 1024);
            }
        }
    };
    auto issueB = [&](int k0, char* panel){
        if (b32) {
            #pragma unroll
            for (int j = 0; j < 4; ++j) {
                const float* p = (const float*)Bt + (long)(n0 + prow[j]) * ldb + k0 + (pscol[j] >> 1);
                RB[j * 2]     = *(const float4*)p;
                RB[j * 2 + 1] = *(const float4*)(p + 4);
            }
        } else {
            #pragma unroll
            for (int j = 0; j < 4; ++j) {
                const char* g = (const char*)Bt + ((long)(n0 + prow[j]) * ldb + k0) * 2 + pscol[j];
                gload16(g, panel + j * 4096 + w * 1024);
            }
        }
    };
    auto writeA = [&](char* panel){
        if (a32) {
            #pragma unroll
            for (int j = 0; j < 4; ++j) {
                int f = (j * 256 + tid) * 16;
                float4 x = RA[j * 2], y = RA[j * 2 + 1];
                v8s v;
                v[0]=f2s(x.x); v[1]=f2s(x.y); v[2]=f2s(x.z); v[3]=f2s(x.w);
                v[4]=f2s(y.x); v[5]=f2s(y.y); v[6]=f2s(y.z); v[7]=f2s(y.w);
                *reinterpret_cast<v8s*>(panel + f) = v;
            }
        }
    };
    auto writeB = [&](char* panel){
        if (b32) {
            #pragma unroll
            for (int j = 0; j < 4; ++j) {
                int f = (j * 256 + tid) * 16;
                float4 x = RB[j * 2], y = RB[j * 2 + 1];
                v8s v;
                v[0]=f2s(x.x); v[1]=f2s(x.y); v[2]=f2s(x.z); v[3]=f2s(x.w);
                v[4]=f2s(y.x); v[5]=f2s(y.y); v[6]=f2s(y.z); v[7]=f2s(y.w);
                *reinterpret_cast<v8s*>(panel + f) = v;
            }
        }
    };

    issueA(0, smc);
    issueB(0, smc + 16384);

    for (int ks = 0; ks < nk; ++ks) {
        char* cur = smc + (ks & 1) * 32768;
        asm volatile("s_waitcnt vmcnt(0)" ::: "memory");   // L(ks) landed (regs + LDS)
        writeA(cur);
        writeB(cur + 16384);
        sync_nodrain();
        if (ks + 1 < nk) {
            char* nxt = smc + ((ks + 1) & 1) * 32768;
            issueA((ks + 1) << 6, nxt);
            issueB((ks + 1) << 6, nxt + 16384);
        }
        v8s af[8], bfr[8];
        #pragma unroll
        for (int mt = 0; mt < 4; ++mt) {
            int row = wm * 64 + mt * 16 + l15;
            int sw = (row & 7) << 4;
            af[mt * 2]     = *reinterpret_cast<const v8s*>(cur + row * 128 + ((quad * 16) ^ sw));
            af[mt * 2 + 1] = *reinterpret_cast<const v8s*>(cur + row * 128 + ((64 + quad * 16) ^ sw));
        }
        #pragma unroll
        for (int nt = 0; nt < 4; ++nt) {
            int row = wn * 64 + nt * 16 + l15;
            int sw = (row & 7) << 4;
            bfr[nt * 2]     = *reinterpret_cast<const v8s*>(cur + 16384 + row * 128 + ((quad * 16) ^ sw));
            bfr[nt * 2 + 1] = *reinterpret_cast<const v8s*>(cur + 16384 + row * 128 + ((64 + quad * 16) ^ sw));
        }
        __builtin_amdgcn_s_setprio(1);
        #pragma unroll
        for (int ks2 = 0; ks2 < 2; ++ks2)
            #pragma unroll
            for (int mt = 0; mt < 4; ++mt)
                #pragma unroll
                for (int nt = 0; nt < 4; ++nt)
                    acc[mt * 4 + nt] = mfma16(af[mt * 2 + ks2], bfr[nt * 2 + ks2], acc[mt * 4 + nt]);
        __builtin_amdgcn_s_setprio(0);
    }

    #pragma unroll
    for (int mt = 0; mt < 4; ++mt)
        #pragma unroll
        for (int nt = 0; nt < 4; ++nt)
            #pragma unroll
            for (int r = 0; r < 4; ++r) {
                long off = (long)(m0 + wm * 64 + mt * 16 + quad * 4 + r) * ldc + n0 + wn * 64 + nt * 16 + l15;
                if (c32) ((float*)C)[off] = acc[mt * 4 + nt][r];
                else     ((bf16*)C)[off] = f2bf(acc[mt * 4 + nt][r]);
            }
}

// ---------------- generic GEMM: C = A @ Bt^T (64² tile; G3 only) ----------------
__global__ __launch_bounds__(256) void gemm_bt(
    const void* __restrict__ A, long lda, long strideA, int aExt,
    const void* __restrict__ Bt, long ldb, long strideB, int bExt,
    void* __restrict__ C, long ldc, long strideC, int cExt,
    int K, const int* __restrict__ gf)
{
    const bool f32 = (*gf == 0);
    const bool a32 = aExt && f32, b32 = bExt && f32, c32 = cExt && f32;
    __shared__ bf16 As[2][64][40];
    __shared__ bf16 Bs[2][64][40];
    const int tid = threadIdx.x;
    const int w = tid >> 6, lane = tid & 63, quad = lane >> 4, l15 = lane & 15;
    const long aoff = (long)blockIdx.z * strideA;
    const long boff = (long)blockIdx.z * strideB;
    const long coff = (long)blockIdx.z * strideC;
    const int m0 = blockIdx.y * 64, n0 = blockIdx.x * 64;
    const int lr = tid >> 2, lc = (tid & 3) * 8;

    v4f acc[4];
    #pragma unroll
    for (int i = 0; i < 4; ++i) acc[i] = vzero();

    v8s av = ld8(A,  aoff + (long)(m0 + lr) * lda + lc, a32);
    v8s bv = ld8(Bt, boff + (long)(n0 + lr) * ldb + lc, b32);

    for (int k0 = 0; k0 < K; k0 += 32) {
        const int bi = (k0 >> 5) & 1;
        *reinterpret_cast<v8s*>(&As[bi][lr][lc]) = av;
        *reinterpret_cast<v8s*>(&Bs[bi][lr][lc]) = bv;
        if (k0 + 32 < K) {
            av = ld8(A,  aoff + (long)(m0 + lr) * lda + k0 + 32 + lc, a32);
            bv = ld8(Bt, boff + (long)(n0 + lr) * ldb + k0 + 32 + lc, b32);
        }
        __syncthreads();
        v8s af = *reinterpret_cast<const v8s*>(&As[bi][w * 16 + l15][quad * 8]);
        #pragma unroll
        for (int nt = 0; nt < 4; ++nt) {
            v8s bfv = *reinterpret_cast<const v8s*>(&Bs[bi][nt * 16 + l15][quad * 8]);
            acc[nt] = mfma16(af, bfv, acc[nt]);
        }
    }
    #pragma unroll
    for (int nt = 0; nt < 4; ++nt)
        #pragma unroll
        for (int r = 0; r < 4; ++r) {
            long off = coff + (long)(m0 + w * 16 + quad * 4 + r) * ldc + n0 + nt * 16 + l15;
            if (c32) ((float*)C)[off] = acc[nt][r];
            else     ((bf16*)C)[off] = f2bf(acc[nt][r]);
        }
}

// ---------------- RMSNorm width 1536 ----
__global__ __launch_bounds__(256) void rmsnorm_q(
    const bf16* __restrict__ in, const void* __restrict__ wt, bf16* __restrict__ out,
    const int* __restrict__ gf)
{
    const bool f32 = (*gf == 0);
    int row = blockIdx.x;
    const bf16* x = in + (long)row * QL_;
    float v[6]; float ss = 0.f;
    #pragma unroll
    for (int i = 0; i < 6; ++i) { v[i] = bf2f(x[threadIdx.x + i * 256]); ss += v[i] * v[i]; }
    #pragma unroll
    for (int off = 1; off < 64; off <<= 1) ss += __shfl_xor(ss, off);
    __shared__ float ws4[4];
    if ((threadIdx.x & 63) == 0) ws4[threadIdx.x >> 6] = ss;
    __syncthreads();
    float rs = rsqrtf((ws4[0] + ws4[1] + ws4[2] + ws4[3]) / (float)QL_ + 1e-6f);
    bf16* o = out + (long)row * QL_;
    #pragma unroll
    for (int i = 0; i < 6; ++i) {
        int c = threadIdx.x + i * 256;
        o[c] = f2bf(v[i] * rs * ld1(wt, c, f32));
    }
}

// ---------------- kv: rmsnorm(512) + rope(64) ----------------
__global__ __launch_bounds__(256) void kv_proc(
    bf16* __restrict__ kvf, const void* __restrict__ wt,
    const void* __restrict__ fcos, const void* __restrict__ fsin,
    const int* __restrict__ gf)
{
    const bool f32 = (*gf == 0);
    int row = blockIdx.x;             // b*2048 + s
    int s = row & (S_ - 1);
    bf16* x = kvf + (long)row * DQK_;
    float v[2]; float ss = 0.f;
    #pragma unroll
    for (int i = 0; i < 2; ++i) { v[i] = bf2f(x[threadIdx.x + i * 256]); ss += v[i] * v[i]; }
    #pragma unroll
    for (int off = 1; off < 64; off <<= 1) ss += __shfl_xor(ss, off);
    __shared__ float ws4[4];
    if ((threadIdx.x & 63) == 0) ws4[threadIdx.x >> 6] = ss;
    __syncthreads();
    float rs = rsqrtf((ws4[0] + ws4[1] + ws4[2] + ws4[3]) / (float)KVL_ + 1e-6f);
    #pragma unroll
    for (int i = 0; i < 2; ++i) {
        int c = threadIdx.x + i * 256;
        x[c] = f2bf(v[i] * rs * ld1(wt, c, f32));
    }
    if (threadIdx.x < 32) {
        int i = threadIdx.x;
        float x0 = bf2f(x[KVL_ + 2 * i]), x1 = bf2f(x[KVL_ + 2 * i + 1]);
        float c = ld1(fcos, s * 32 + i, f32), sn = ld1(fsin, s * 32 + i, f32);
        x[KVL_ + 2 * i]     = f2bf(x0 * c - x1 * sn);
        x[KVL_ + 2 * i + 1] = f2bf(x0 * sn + x1 * c);
    }
}

// ---------------- q pack ----
__global__ __launch_bounds__(512) void q_pack(
    const bf16* __restrict__ qfull, const void* __restrict__ fcos, const void* __restrict__ fsin,
    bf16* __restrict__ qnope, bf16* __restrict__ qpe, const int* __restrict__ gf)
{
    const bool f32 = (*gf == 0);
    int row = blockIdx.x;             // b*2048 + s
    int s = row & (S_ - 1);
    int b = row >> 11;
    const bf16* q = qfull + (long)row * (H_ * QKH_);
    int t = threadIdx.x;
    {   // rope
        int h = t >> 5, i = t & 31;
        float x0 = bf2f(q[h * QKH_ + NOPE_ + 2 * i]);
        float x1 = bf2f(q[h * QKH_ + NOPE_ + 2 * i + 1]);
        float c = ld1(fcos, s * 32 + i, f32), sn = ld1(fsin, s * 32 + i, f32);
        bf16* dst = qpe + ((long)(h * B_ + b) * S_ + s) * ROPE_;
        dst[2 * i]     = f2bf(x0 * c - x1 * sn);
        dst[2 * i + 1] = f2bf(x0 * sn + x1 * c);
    }
    if (t < 256) {  // nope copy
        int h = t >> 4, d0 = (t & 15) * 8;
        v8s v = *reinterpret_cast<const v8s*>(q + h * QKH_ + d0);
        *reinterpret_cast<v8s*>(qnope + ((long)h * 4096 + row) * NOPE_ + d0) = v;
    }
}

// ---------------- V transpose: kvf[:, :512] -> Vt (B, 512, S) ----------------
__global__ __launch_bounds__(256) void v_transpose(
    const bf16* __restrict__ kcomb, bf16* __restrict__ vt)
{
    __shared__ bf16 tile[64][72];
    int b = blockIdx.z, t0 = blockIdx.x * 64, c0 = blockIdx.y * 64;
    int tid = threadIdx.x;
    int r = tid >> 2, sg = tid & 3;
    const bf16* src = kcomb + ((long)b * S_ + t0 + r) * DQK_ + c0 + sg * 16;
    #pragma unroll
    for (int i = 0; i < 2; ++i)
        *reinterpret_cast<v8s*>(&tile[r][sg * 16 + i * 8]) = reinterpret_cast<const v8s*>(src)[i];
    __syncthreads();
    int c = tid >> 2;
    bf16* dst = vt + ((long)b * KVL_ + c0 + c) * S_ + t0 + sg * 16;
    bf16 tmp[16];
    #pragma unroll
    for (int i = 0; i < 16; ++i) tmp[i] = tile[sg * 16 + i][c];
    #pragma unroll
    for (int i = 0; i < 2; ++i)
        reinterpret_cast<v8s*>(dst)[i] = *reinterpret_cast<v8s*>(&tmp[i * 8]);
}

// ---------------- wkv_b nope rows transpose ----------------
__global__ __launch_bounds__(256) void wkvb_t_kernel(
    const void* __restrict__ wkvb, bf16* __restrict__ outp, const int* __restrict__ gf)
{
    const bool f32 = (*gf == 0);
    long idx = (long)blockIdx.x * 256 + threadIdx.x;  // 16*512*128
    int h = (int)(idx >> 16);
    int rem = (int)(idx & 65535);
    int c = rem >> 7, d = rem & 127;
    outp[idx] = f2bf(ld1(wkvb, ((long)(h * 256 + d)) * KVL_ + c, f32));
}

// ---------------- flash attention: 8-wave, KEY-SPLIT QK, PAIRED q-tiles (R11) ----------------
// Triangular pairing: block bx (0..15) processes q-tiles qb = 31-bx (long, 32-bx units)
// then qb = bx (short, bx+1 units) -> every block does exactly 33 kb-iterations.
// Grid 512 uniform blocks = 2 equal sequential blocks per CU (1-block/CU LDS residency):
// removes the triangular-drain CU-idle that capped occupancy-time at ~54% of ceiling.
// Body per half is the verified R9/R10 kernel (key-split QK, ctx-split PV, 3 counted
// barriers/kb). Cross-half hazards: Qn stage (B17408-34816) doesn't overlap Mrg (B94208+);
// Wt stage overlaps Mrg but is preceded by prologue's sync_nodrain (orders after Mrg
// reads); no gload_lds in flight across the boundary (last kb has no K-prefetch).
__global__ __launch_bounds__(512, 2) void attn(
    const bf16* __restrict__ qnope, // (H, 4096, 128)
    const bf16* __restrict__ qpe,   // (H*B, S, 64)
    const bf16* __restrict__ kc,    // (B, S, 576)
    const bf16* __restrict__ vt,    // (B, 512, S)
    const bf16* __restrict__ wkvbt, // (H, 512, 128)
    const void* __restrict__ wkvb,  // external (H*256, 512); rows h*256+128.. = wv
    bf16* __restrict__ oheads,      // (4096, 2048), head h at cols h*128..
    const int* __restrict__ gf)
{
    __shared__ __align__(16) bf16 sm[78848];      // 157696 B
    char* smc = (char*)sm;
    const bool e32 = (*gf == 0);
    const int tid = threadIdx.x;
    const int w = tid >> 6, lane = tid & 63, quad = lane >> 4, l15 = lane & 15;
    const int wr = w & 3, wc = w >> 2;
    const int bx = blockIdx.x;                    // 0..15
    const int bh = blockIdx.y;                    // h*B + b
    const int b = bh & (B_ - 1), h = bh >> 1;

    // ---- loop-invariant staging voffsets (pre-swizzled source; linear LDS dest)
    const char* KbB = (const char*)(kc + (long)b * S_ * DQK_);
    const char* VbB = (const char*)(vt + (long)b * KVL_ * S_);
    unsigned srcK[9], srcV[8];
    #pragma unroll
    for (int j = 0; j < 9; ++j) {   // K tile [64][1152B]
        unsigned f = (unsigned)((j * 512 + tid) * 16);
        unsigned row = f / 1152u;
        unsigned col = f - row * 1152u;
        srcK[j] = row * 1152u + (col ^ ((row & 7u) << 4));
    }
    #pragma unroll
    for (int j = 0; j < 8; ++j) {   // V tile [512][128B]
        unsigned f = (unsigned)((j * 512 + tid) * 16);
        unsigned row = f >> 7, col = f & 127u;
        srcV[j] = row * (unsigned)(S_ * 2) + (col ^ ((row & 7u) << 4));
    }
    const unsigned swz = (unsigned)((l15 & 7) << 4);
    bf16* Ps_wr = sm + 69632 + wr * 1152;      // per-wr SHARED [16][72]
    char* Ps_wrB = (char*)Ps_wr;
    float* MexM = (float*)(sm + 74240);        // [2][64]
    float* MexS = (float*)(sm + 74496);        // [2][64]
    float* Mrg  = (float*)(smc + 94208);       // [4][16][128]

    #pragma unroll 1
    for (int half = 0; half < 2; ++half) {
        const int qb = half ? bx : (31 - bx);
        const int q0 = qb * 64;
        const int nkb = qb + 1;

        // ---- prologue: q_abs = qnope_tile @ wkvbt_h^T -> qreg[18] A-frags
        #pragma unroll
        for (int i = 0; i < 2; ++i) {   // stage Qn (64x128 -> [64][136])
            int a = tid + i * 512, rr = a >> 4, sg = a & 15;
            *reinterpret_cast<v8s*>(&sm[8704 + rr * 136 + sg * 8]) =
                *reinterpret_cast<const v8s*>(qnope + ((long)h * 4096 + b * 2048 + q0 + rr) * NOPE_ + sg * 8);
        }
        v8s qreg[18];
        for (int p = 0; p < 4; ++p) {
            sync_nodrain();
            #pragma unroll
            for (int i = 0; i < 4; ++i) {   // stage Wt: 128 rows (c-dim) x 128 (d-dim)
                int a = tid + i * 512, rr = a >> 4, sg = a & 15;
                *reinterpret_cast<v8s*>(&sm[17408 + rr * 136 + sg * 8]) =
                    *reinterpret_cast<const v8s*>(wkvbt + ((long)h * 512 + p * 128 + rr) * NOPE_ + sg * 8);
            }
            sync_nodrain();
            v4f qacc[4];
            #pragma unroll
            for (int i = 0; i < 4; ++i) qacc[i] = vzero();
            #pragma unroll
            for (int kk = 0; kk < 4; ++kk) {
                v8s aq = *reinterpret_cast<const v8s*>(&sm[8704 + (wr * 16 + l15) * 136 + kk * 32 + quad * 8]);
                #pragma unroll
                for (int nt = 0; nt < 4; ++nt) {
                    v8s bw = *reinterpret_cast<const v8s*>(&sm[17408 + (wc * 64 + nt * 16 + l15) * 136 + kk * 32 + quad * 8]);
                    qacc[nt] = mfma16(aq, bw, qacc[nt]);
                }
            }
            #pragma unroll
            for (int nt = 0; nt < 4; ++nt)
                #pragma unroll
                for (int r = 0; r < 4; ++r)
                    sm[(wr * 16 + quad * 4 + r) * 136 + wc * 64 + nt * 16 + l15] = f2bf(qacc[nt][r]);
            sync_nodrain();
            #pragma unroll
            for (int c2 = 0; c2 < 2; ++c2)
                #pragma unroll
                for (int ks = 0; ks < 2; ++ks)
                    qreg[p * 4 + c2 * 2 + ks] =
                        *reinterpret_cast<const v8s*>(&sm[(wr * 16 + l15) * 136 + c2 * 64 + ks * 32 + quad * 8]);
        }
        {   // qpe fragments (d 512..575)
            const bf16* qp = qpe + ((long)bh * S_ + q0 + wr * 16 + l15) * ROPE_;
            qreg[16] = *reinterpret_cast<const v8s*>(qp + quad * 8);
            qreg[17] = *reinterpret_cast<const v8s*>(qp + 32 + quad * 8);
        }
        sync_nodrain();   // prologue LDS reads done before K(0) staging lands

        // issue K(0)
        #pragma unroll
        for (int j = 0; j < 9; ++j)
            gload16(KbB + srcK[j], smc + j * 8192 + w * 1024);

        float m_run[4], l_run[4];
        v4f o[16];
        #pragma unroll
        for (int i = 0; i < 16; ++i) o[i] = vzero();
        #pragma unroll
        for (int r = 0; r < 4; ++r) { m_run[r] = -3e38f; l_run[r] = 0.f; }

        for (int kb = 0; kb < nkb; ++kb) {
            const int t0 = kb * 64;

            BAR_VM(0);   // K(kb) resident; all waves past PV(kb-1)

            // issue V(kb): flies under QK^T + softmax
            {
                const char* vb = VbB + (long)t0 * 2;
                #pragma unroll
                for (int j = 0; j < 8; ++j)
                    gload16(vb + srcV[j], smc + 73728 + j * 8192 + w * 1024);
            }

            // ---- QK^T: 36 MFMAs, key-split (wave owns keys wc*32..+31)
            v4f sacc[2];
            sacc[0] = vzero(); sacc[1] = vzero();
            const char* kr = smc + (unsigned)(l15 * 1152) + (unsigned)(wc * 2) * 18432u;
            __builtin_amdgcn_s_setprio(1);
            #pragma unroll
            for (int g = 0; g < 18; ++g) {
                v8s aq = qreg[g];
                unsigned a0 = ((unsigned)(g * 64 + quad * 16)) ^ swz;
                sacc[0] = mfma16(aq, *reinterpret_cast<const v8s*>(kr + a0), sacc[0]);
                sacc[1] = mfma16(aq, *reinterpret_cast<const v8s*>(kr + 18432 + a0), sacc[1]);
            }
            __builtin_amdgcn_s_setprio(0);

            // ---- scale + causal mask (wave's 32 keys)
            #pragma unroll
            for (int ntl = 0; ntl < 2; ++ntl) {
                int col = t0 + (wc * 2 + ntl) * 16 + l15;
                #pragma unroll
                for (int r = 0; r < 4; ++r) {
                    int row = q0 + wr * 16 + quad * 4 + r;
                    float s = sacc[ntl][r] * SCALE_;
                    sacc[ntl][r] = (col <= row) ? s : -3e38f;
                }
            }
            // ---- partial row-max over wave's 32 keys -> MexM (before barrier)
            v4f mxv;
            #pragma unroll
            for (int r = 0; r < 4; ++r) {
                float m = fmaxf(sacc[0][r], sacc[1][r]);
                m = fmaxf(m, __shfl_xor(m, 1));
                m = fmaxf(m, __shfl_xor(m, 2));
                m = fmaxf(m, __shfl_xor(m, 4));
                m = fmaxf(m, __shfl_xor(m, 8));
                mxv[r] = m;
            }
            if (l15 == 0) *reinterpret_cast<v4f*>(&MexM[wc * 64 + wr * 16 + quad * 4]) = mxv;

            sync_nodrain();   // K region free + m-exchange visible
            if (kb + 1 < nkb) {   // issue K(kb+1): flies under softmax + PV
                const char* kbn = KbB + (long)(t0 + 64) * 1152;
                #pragma unroll
                for (int j = 0; j < 9; ++j)
                    gload16(kbn + srcK[j], smc + j * 8192 + w * 1024);
            }

            // ---- merged max + exact defer-rescale
            v4f ma = *reinterpret_cast<const v4f*>(&MexM[wr * 16 + quad * 4]);
            v4f mb = *reinterpret_cast<const v4f*>(&MexM[64 + wr * 16 + quad * 4]);
            float mfull[4]; int need = 0;
            #pragma unroll
            for (int r = 0; r < 4; ++r) {
                mfull[r] = fmaxf(ma[r], mb[r]);
                need |= (mfull[r] > m_run[r]) ? 1 : 0;
            }
            if (__any(need)) {
                #pragma unroll
                for (int r = 0; r < 4; ++r) {
                    float mnew = fmaxf(m_run[r], mfull[r]);
                    float al = exp2f((m_run[r] - mnew) * LOG2E);
                    m_run[r] = mnew;
                    l_run[r] *= al;
                    #pragma unroll
                    for (int i = 0; i < 16; ++i) o[i][r] *= al;
                }
            }
            // ---- exp + partial row-sum + P write (shared per wr)
            v4f rsv;
            #pragma unroll
            for (int r = 0; r < 4; ++r) rsv[r] = 0.f;
            #pragma unroll
            for (int ntl = 0; ntl < 2; ++ntl)
                #pragma unroll
                for (int r = 0; r < 4; ++r) {
                    float pv = exp2f((sacc[ntl][r] - m_run[r]) * LOG2E);
                    rsv[r] += pv;
                    Ps_wr[(quad * 4 + r) * 72 + (wc * 2 + ntl) * 16 + l15] = f2bf(pv);
                }
            #pragma unroll
            for (int r = 0; r < 4; ++r) {
                float t = rsv[r];
                t += __shfl_xor(t, 1);
                t += __shfl_xor(t, 2);
                t += __shfl_xor(t, 4);
                t += __shfl_xor(t, 8);
                rsv[r] = t;
            }
            if (l15 == 0) *reinterpret_cast<v4f*>(&MexS[wc * 64 + wr * 16 + quad * 4]) = rsv;

            // ---- V ready + s-exchange visible (K(kb+1)'s 9 loads stay in flight)
            if (kb + 1 < nkb) { BAR_VM(9); } else { BAR_VM(0); }
            {
                v4f sa = *reinterpret_cast<const v4f*>(&MexS[wr * 16 + quad * 4]);
                v4f sb = *reinterpret_cast<const v4f*>(&MexS[64 + wr * 16 + quad * 4]);
                #pragma unroll
                for (int r = 0; r < 4; ++r) l_run[r] += sa[r] + sb[r];
            }

            // ---- PV: 32 MFMAs from swizzled V tile (wave's ctx half); P from shared Ps_wr
            v8s pa0 = *reinterpret_cast<const v8s*>(Ps_wrB + l15 * 144 + quad * 16);
            v8s pa1 = *reinterpret_cast<const v8s*>(Ps_wrB + l15 * 144 + 64 + quad * 16);
            const char* vr = smc + 73728 + (unsigned)((wc * 256 + l15) * 128);
            __builtin_amdgcn_s_setprio(1);
            #pragma unroll
            for (int ks = 0; ks < 2; ++ks) {
                v8s pa = ks ? pa1 : pa0;
                unsigned a0 = ((unsigned)(ks * 64 + quad * 16)) ^ swz;
                #pragma unroll
                for (int nt = 0; nt < 16; ++nt) {
                    v8s bv = *reinterpret_cast<const v8s*>(vr + nt * 2048 + a0);
                    o[nt] = mfma16(pa, bv, o[nt]);
                }
            }
            __builtin_amdgcn_s_setprio(0);
        }

        // ---- epilogue: out_h = (o/l) @ wv_h^T; each wave K=256 partial, exact f32 merge
        sync_nodrain();
        float inv[4];
        #pragma unroll
        for (int r = 0; r < 4; ++r) inv[r] = 1.0f / l_run[r];
        // Po @0: [64][520]
        #pragma unroll
        for (int i = 0; i < 16; ++i)
            #pragma unroll
            for (int r = 0; r < 4; ++r)
                sm[(wr * 16 + quad * 4 + r) * 520 + wc * 256 + i * 16 + l15] = f2bf(o[i][r] * inv[r]);
        v4f oacc[8];
        #pragma unroll
        for (int i = 0; i < 8; ++i) oacc[i] = vzero();

        for (int kcc = 0; kcc < 8; ++kcc) {
            sync_nodrain();
            #pragma unroll
            for (int i = 0; i < 2; ++i) {   // stage both wv halves: [2][128][40]
                int a = wr * 64 + lane + i * 256, rr = a >> 2, sg = a & 3;
                *reinterpret_cast<v8s*>(&sm[36864 + wc * 5120 + rr * 40 + sg * 8]) =
                    ld8(wkvb, (long)(h * 256 + 128 + rr) * KVL_ + wc * 256 + kcc * 32 + sg * 8, e32);
            }
            sync_nodrain();
            v8s aq = *reinterpret_cast<const v8s*>(&sm[(wr * 16 + l15) * 520 + wc * 256 + kcc * 32 + quad * 8]);
            #pragma unroll
            for (int nt = 0; nt < 8; ++nt) {
                v8s bw = *reinterpret_cast<const v8s*>(&sm[36864 + wc * 5120 + (nt * 16 + l15) * 40 + quad * 8]);
                oacc[nt] = mfma16(aq, bw, oacc[nt]);
            }
        }
        // merge: wc=1 writes f32 partial, wc=0 adds and stores
        if (wc == 1) {
            #pragma unroll
            for (int nt = 0; nt < 8; ++nt)
                #pragma unroll
                for (int r = 0; r < 4; ++r)
                    Mrg[wr * 2048 + (quad * 4 + r) * 128 + nt * 16 + l15] = oacc[nt][r];
        }
        sync_nodrain();
        if (wc == 0) {
            #pragma unroll
            for (int nt = 0; nt < 8; ++nt)
                #pragma unroll
                for (int r = 0; r < 4; ++r)
                    oheads[(long)(b * S_ + q0 + wr * 16 + quad * 4 + r) * 2048 + h * 128 + nt * 16 + l15] =
                        f2bf(oacc[nt][r] + Mrg[wr * 2048 + (quad * 4 + r) * 128 + nt * 16 + l15]);
        }
    }
}

extern "C" void kernel_launch(void* const* d_in, const int* in_sizes, int n_in,
                              void* d_out, int out_size, void* d_ws, size_t ws_size,
                              hipStream_t stream) {
    const void* x     = d_in[0];
    const void* fcos  = d_in[1];
    const void* fsin  = d_in[2];
    // d_in[3] = mask (causal) — implemented directly
    const void* wq_a  = d_in[4];
    const void* q_ln  = d_in[5];
    const void* wq_b  = d_in[6];
    const void* wkv_a = d_in[7];
    const void* kv_ln = d_in[8];
    const void* wkv_b = d_in[9];
    const void* wo    = d_in[10];

    // workspace (bf16 elems), peak 30,670,864 elems ~= 58.5 MiB
    bf16* W = (bf16*)d_ws;
    bf16* t0     = W;                 // 6,291,456 (dead after GEMM2)
    bf16* qnope  = W;                 // 8,388,608 (written by q_pack, after t0 dead)
    bf16* qpe    = W + 8388608L;      // 4,194,304
    bf16* qfull  = W + 12582912L;     // 12,582,912 (dead after q_pack)
    bf16* oheads = W + 12582912L;     // 8,388,608 (over qfull)
    bf16* kvf    = W + 25165824L;     // 2,359,296
    bf16* vtb    = W + 27525120L;     // 2,097,152
    bf16* wkvbt  = W + 29622272L;     // 1,048,576
    int*  gflag  = (int*)(W + 30670848L);

    detect_k<<<dim3(1), dim3(64), 0, stream>>>((const unsigned*)fcos, gflag);
    wkvb_t_kernel<<<dim3(4096), dim3(256), 0, stream>>>(wkv_b, wkvbt, gflag);

    // GEMM1: t0 = x @ wq_a^T   (4096 x 1536 x 2048)  [128², BK=64, 384 blocks]
    gemm128<<<dim3(12, 32), dim3(256), 0, stream>>>(
        x, 2048L, 1, wq_a, 2048L, 1, t0, 1536L, 0, 2048, gflag);
    rmsnorm_q<<<dim3(4096), dim3(256), 0, stream>>>(t0, q_ln, t0, gflag);

    // GEMM2: qfull = t0 @ wq_b^T  (4096 x 3072 x 1536)  [128², BK=64, 768 blocks]
    gemm128<<<dim3(24, 32), dim3(256), 0, stream>>>(
        t0, 1536L, 0, wq_b, 1536L, 1, qfull, 3072L, 0, 1536, gflag);

    // GEMM3: kvf = x @ wkv_a^T  (4096 x 576 x 2048)  [64² tile, N not /128]
    gemm_bt<<<dim3(9, 64, 1), dim3(256), 0, stream>>>(
        x, 2048L, 0L, 1, wkv_a, 2048L, 0L, 1, kvf, 576L, 0L, 0, 2048, gflag);

    q_pack<<<dim3(4096), dim3(512), 0, stream>>>(qfull, fcos, fsin, qnope, qpe, gflag);
    kv_proc<<<dim3(4096), dim3(256), 0, stream>>>(kvf, kv_ln, fcos, fsin, gflag);
    v_transpose<<<dim3(32, 8, 2), dim3(256), 0, stream>>>(kvf, vtb);

    // attention, paired q-tiles: 16x32 grid, every block = 33 kb-iterations
    attn<<<dim3(16, 32), dim3(512), 0, stream>>>(
        qnope, qpe, kvf, vtb, wkvbt, wkv_b, oheads, gflag);

    // GEMM7: out = oheads @ wo^T  (4096 x 2048 x 2048)  [128², BK=64, 512 blocks]
    gemm128<<<dim3(16, 32), dim3(256), 0, stream>>>(
        oheads, 2048L, 0, wo, 2048L, 1, d_out, 2048L, 1, 2048, gflag);
}